// Round 1
// baseline (175.490 us; speedup 1.0000x reference)
//
#include <hip/hip_runtime.h>
#include <math.h>

// Problem constants
#define LSEQ 2048          // sequence length L (also FFT size N)
#define HCH  512           // channels H
#define NST  64            // state size N
#define NBATCH 8           // batch B

// ---------------------------------------------------------------------------
// Radix-2 Stockham FFT, N=2048 complex, 256 threads, LDS ping-pong.
// Forward: e^{-2pi i k n / N} (numpy convention). inverse=1 uses conj
// twiddles (unnormalized inverse; caller scales by 1/N).
// Returns pointer to buffer holding the (natural-order) result.
// ---------------------------------------------------------------------------
__device__ float2* fft2048(float2* src, float2* dst, int inverse)
{
    const int tid = threadIdx.x;
    for (int stage = 0; stage < 11; ++stage) {
        const int Ns = 1 << stage;
        const float astep = -(float)M_PI / (float)Ns;
        __syncthreads();
#pragma unroll
        for (int q = 0; q < 4; ++q) {
            const int j  = tid + (q << 8);       // 0..1023
            const int jm = j & (Ns - 1);
            float2 a = src[j];
            float2 b = src[j + 1024];
            float s, c;
            __sincosf(astep * (float)jm, &s, &c);
            if (inverse) s = -s;
            const float tr = c * b.x - s * b.y;
            const float ti = c * b.y + s * b.x;
            const int d0 = ((j >> stage) << (stage + 1)) + jm;
            dst[d0]      = make_float2(a.x + tr, a.y + ti);
            dst[d0 + Ns] = make_float2(a.x - tr, a.y - ti);
        }
        float2* t = src; src = dst; dst = t;
    }
    __syncthreads();
    return src;
}

// ---------------------------------------------------------------------------
// Kernel 1: per channel h, compute at_roots (Cauchy generating function),
// ifft -> K (real, length 2048), then Kf = rfft(K, n=4096) -> ws (2049 c64).
// ---------------------------------------------------------------------------
__global__ __launch_bounds__(256)
void s4_kf_kernel(const float* __restrict__ Lr, const float* __restrict__ Li,
                  const float* __restrict__ Pr, const float* __restrict__ Pi,
                  const float* __restrict__ Br, const float* __restrict__ Bi,
                  const float* __restrict__ Cr, const float* __restrict__ Ci,
                  const float* __restrict__ log_dt, float2* __restrict__ Kf)
{
    __shared__ float2 bufA[2048];
    __shared__ float2 bufB[2048];
    __shared__ float  lamRe[NST], lamIm[NST], q1s[NST];
    __shared__ float2 w00s[NST], w01s[NST], q0s[NST];

    const int h   = blockIdx.x;
    const int tid = threadIdx.x;

    if (tid < NST) {
        const int n = tid;
        const float pr = Pr[n], pi = Pi[n], br = Br[n], bi = Bi[n];
        lamRe[n] = Lr[n];
        lamIm[n] = Li[n];
        // q0 = conj(P)*B ; q1 = conj(P)*P = |P|^2 (real)
        q0s[n] = make_float2(pr * br + pi * bi, pr * bi - pi * br);
        q1s[n] = pr * pr + pi * pi;
        const float cr = Cr[h * NST + n], ci = Ci[h * NST + n];
        // w00 = conj(C_h)*B ; w01 = conj(C_h)*P
        w00s[n] = make_float2(cr * br + ci * bi, cr * bi - ci * br);
        w01s[n] = make_float2(cr * pr + ci * pi, cr * pi - ci * pr);
    }
    __syncthreads();

    const float dt = expf(log_dt[h]);
    const float a  = 2.0f / dt;

    // at_roots[l] into bufA.  g = i*a*t, c2 = 1 + i*t, t = tan(pi*l/2048)
    for (int q = 0; q < 8; ++q) {
        const int l = tid + (q << 8);
        const float t   = tanf((float)M_PI * (float)l * (1.0f / 2048.0f));
        const float at_ = a * t;
        float k00r = 0.f, k00i = 0.f, k01r = 0.f, k01i = 0.f;
        float k10r = 0.f, k10i = 0.f, k11r = 0.f, k11i = 0.f;
#pragma unroll 8
        for (int n = 0; n < NST; ++n) {
            const float x = -lamRe[n];
            const float y = at_ - lamIm[n];
            const float inv = __builtin_amdgcn_rcpf(x * x + y * y);
            const float rr = x * inv, ri = -y * inv;   // r = 1/(g - lambda)
            float2 w;
            w = w00s[n]; k00r += w.x * rr - w.y * ri; k00i += w.x * ri + w.y * rr;
            w = w01s[n]; k01r += w.x * rr - w.y * ri; k01i += w.x * ri + w.y * rr;
            w = q0s[n];  k10r += w.x * rr - w.y * ri; k10i += w.x * ri + w.y * rr;
            const float q1 = q1s[n]; k11r += q1 * rr; k11i += q1 * ri;
        }
        const float dr = 1.0f + k11r, di = k11i;
        const float dinv = __builtin_amdgcn_rcpf(dr * dr + di * di);
        const float pr_ = k01r * k10r - k01i * k10i;
        const float pi_ = k01r * k10i + k01i * k10r;
        const float qr = (pr_ * dr + pi_ * di) * dinv;
        const float qi = (pi_ * dr - pr_ * di) * dinv;
        const float sr = k00r - qr, si = k00i - qi;
        // at = (1 + i t) * (sr + i si)
        bufA[l] = make_float2(sr - t * si, si + t * sr);
    }

    // K = Re(ifft(at)) / 2048
    float2* Kt = fft2048(bufA, bufB, 1);   // unnormalized inverse -> bufB

    // pack z[n] = K[2n] + i K[2n+1] (n<1024), zero tail -> bufA
    const float sc = 1.0f / 2048.0f;
    for (int n = tid; n < 1024; n += 256)
        bufA[n] = make_float2(Kt[2 * n].x * sc, Kt[2 * n + 1].x * sc);
    for (int n = 1024 + tid; n < 2048; n += 256)
        bufA[n] = make_float2(0.f, 0.f);

    float2* Z = fft2048(bufA, bufB, 0);    // forward -> bufB

    // unpack rfft-4096: Kf[k] = Ze + e^{-2pi i k/4096} Zo
    float2* __restrict__ out = Kf + (size_t)h * 2049;
    for (int k = tid; k < 1024; k += 256) {
        const float2 Zk = Z[k];
        const float2 Zm = Z[(2048 - k) & 2047];
        const float zer = 0.5f * (Zk.x + Zm.x), zei = 0.5f * (Zk.y - Zm.y);
        const float zdr = Zk.x - Zm.x,         zdi = Zk.y + Zm.y;
        const float zor = 0.5f * zdi,          zoi = -0.5f * zdr;
        float s, c;
        __sincosf(-(float)M_PI * (float)k * (1.0f / 2048.0f), &s, &c);
        const float txr = c * zor - s * zoi;
        const float txi = c * zoi + s * zor;
        out[k] = make_float2(zer + txr, zei + txi);
        if (k > 0) {
            out[2048 - k] = make_float2(zer - txr, txi - zei);  // conj(Ze - tw*Zo)
        } else {
            out[2048] = make_float2(Zk.x - Zk.y, 0.f);          // Ze0 - Zo0
        }
    }
    if (tid == 0) {
        const float2 z = Z[1024];
        out[1024] = make_float2(z.x, -z.y);                      // conj(Z[1024])
    }
}

// ---------------------------------------------------------------------------
// Kernel 3: per (b,h) row: rfft4096(x) -> *Kf -> irfft4096 -> + D*x.
// fastpath: rows contiguous in ws (B,H,L), updated in place.
// slow fallback: strided access directly on u / out.
// ---------------------------------------------------------------------------
__global__ __launch_bounds__(256)
void s4_conv_kernel(const float* __restrict__ u, float* ws_rows,
                    const float2* __restrict__ Kf, const float* __restrict__ Dv,
                    float* __restrict__ out, int fastpath)
{
    __shared__ float2 bufA[2048];
    __shared__ float2 bufB[2048];
    __shared__ float2 yfN;   // Yf[2048]

    const int bh  = blockIdx.x;          // b*512 + h
    const int b   = bh >> 9;
    const int h   = bh & 511;
    const int tid = threadIdx.x;

    // pack x into bufA: z[n] = x[2n] + i x[2n+1], zero tail
    if (fastpath) {
        const float2* rowv = (const float2*)(ws_rows + (size_t)bh * LSEQ);
        for (int n = tid; n < 1024; n += 256) bufA[n] = rowv[n];
    } else {
        const float* ub = u + (size_t)b * LSEQ * HCH + h;
        for (int n = tid; n < 1024; n += 256)
            bufA[n] = make_float2(ub[(size_t)(2 * n) * HCH],
                                  ub[(size_t)(2 * n + 1) * HCH]);
    }
    for (int n = 1024 + tid; n < 2048; n += 256) bufA[n] = make_float2(0.f, 0.f);

    float2* Z = fft2048(bufA, bufB, 0);          // Z in bufB
    const float2* __restrict__ kf = Kf + (size_t)h * 2049;

    // Yf[k] = Xf[k] * Kf[k]  into bufA  (bufA stage data is dead)
    for (int k = tid; k < 1024; k += 256) {
        const float2 Zk = Z[k];
        const float2 Zm = Z[(2048 - k) & 2047];
        const float zer = 0.5f * (Zk.x + Zm.x), zei = 0.5f * (Zk.y - Zm.y);
        const float zdr = Zk.x - Zm.x,          zdi = Zk.y + Zm.y;
        const float zor = 0.5f * zdi,           zoi = -0.5f * zdr;
        float s, c;
        __sincosf(-(float)M_PI * (float)k * (1.0f / 2048.0f), &s, &c);
        const float txr = c * zor - s * zoi;
        const float txi = c * zoi + s * zor;
        const float xr = zer + txr, xi = zei + txi;        // Xf[k]
        const float2 kk = kf[k];
        bufA[k] = make_float2(xr * kk.x - xi * kk.y, xr * kk.y + xi * kk.x);
        if (k > 0) {
            const float mr = zer - txr, mi = txi - zei;    // Xf[2048-k]
            const float2 km = kf[2048 - k];
            bufA[2048 - k] = make_float2(mr * km.x - mi * km.y,
                                         mr * km.y + mi * km.x);
        } else {
            const float x2048 = Zk.x - Zk.y;               // Xf[2048] (real)
            const float2 k2 = kf[2048];
            yfN = make_float2(x2048 * k2.x, x2048 * k2.y);
        }
    }
    if (tid == 0) {
        const float2 z  = Z[1024];
        const float2 kk = kf[1024];
        // Xf[1024] = conj(Z[1024])
        bufA[1024] = make_float2(z.x * kk.x + z.y * kk.y,
                                 z.x * kk.y - z.y * kk.x);
    }
    __syncthreads();

    // W[k] = Ye[k] + i*Yo[k]  into bufB (Z dead)
    for (int k = tid; k < 1024; k += 256) {
        const float2 Yk = bufA[k];
        const float2 Ym = (k == 0) ? yfN : bufA[2048 - k];  // Yf[2048-k]
        const float yer = 0.5f * (Yk.x + Ym.x), yei = 0.5f * (Yk.y - Ym.y);
        const float ydr = Yk.x - Ym.x,          ydi = Yk.y + Ym.y;
        float s, c;
        __sincosf((float)M_PI * (float)k * (1.0f / 2048.0f), &s, &c);  // e^{+2pi i k/4096}
        const float yor = 0.5f * (c * ydr - s * ydi);
        const float yoi = 0.5f * (c * ydi + s * ydr);
        bufB[k] = make_float2(yer - yoi, yei + yor);
        if (k > 0) {
            // u-index 2048-k: e^{+2pi i u/4096} = (-c, s)
            const float yer2 = 0.5f * (Ym.x + Yk.x), yei2 = 0.5f * (Ym.y - Yk.y);
            const float ydr2 = Ym.x - Yk.x,          ydi2 = Ym.y + Yk.y;
            const float yor2 = 0.5f * (-c * ydr2 - s * ydi2);
            const float yoi2 = 0.5f * (-c * ydi2 + s * ydr2);
            bufB[2048 - k] = make_float2(yer2 - yoi2, yei2 + yor2);
        }
    }
    if (tid == 0) {
        const float2 Y = bufA[1024];
        bufB[1024] = make_float2(Y.x, -Y.y);   // conj(Yf[1024])
    }

    float2* w = fft2048(bufB, bufA, 1);        // unnormalized inverse -> bufA
    const float Dh = Dv[h];
    const float sc = 1.0f / 2048.0f;
    if (fastpath) {
        float2* rowv = (float2*)(ws_rows + (size_t)bh * LSEQ);
        for (int n = tid; n < 1024; n += 256) {
            const float2 wv = w[n];
            const float2 xv = rowv[n];
            rowv[n] = make_float2(wv.x * sc + Dh * xv.x,
                                  wv.y * sc + Dh * xv.y);
        }
    } else {
        const float* ub = u + (size_t)b * LSEQ * HCH + h;
        float* ob = out + (size_t)b * LSEQ * HCH + h;
        for (int n = tid; n < 1024; n += 256) {
            const float2 wv = w[n];
            ob[(size_t)(2 * n) * HCH]     = wv.x * sc + Dh * ub[(size_t)(2 * n) * HCH];
            ob[(size_t)(2 * n + 1) * HCH] = wv.y * sc + Dh * ub[(size_t)(2 * n + 1) * HCH];
        }
    }
}

// ---------------------------------------------------------------------------
// Batched 2D transpose: in (B, rows, cols) -> out (B, cols, rows)
// ---------------------------------------------------------------------------
__global__ __launch_bounds__(256)
void transpose_kernel(const float* __restrict__ in, float* __restrict__ out,
                      int rows, int cols)
{
    __shared__ float tile[32][33];
    const int b  = blockIdx.z;
    const int r0 = blockIdx.y << 5;
    const int c0 = blockIdx.x << 5;
    const size_t base = (size_t)b * rows * cols;
    const int tx = threadIdx.x & 31;
    const int ty = threadIdx.x >> 5;
#pragma unroll
    for (int i = 0; i < 32; i += 8)
        tile[ty + i][tx] = in[base + (size_t)(r0 + ty + i) * cols + (c0 + tx)];
    __syncthreads();
#pragma unroll
    for (int i = 0; i < 32; i += 8)
        out[base + (size_t)(c0 + ty + i) * rows + (r0 + tx)] = tile[tx][ty + i];
}

// ---------------------------------------------------------------------------
extern "C" void kernel_launch(void* const* d_in, const int* in_sizes, int n_in,
                              void* d_out, int out_size, void* d_ws, size_t ws_size,
                              hipStream_t stream)
{
    (void)in_sizes; (void)n_in; (void)out_size;
    const float* u  = (const float*)d_in[0];
    const float* Lr = (const float*)d_in[1];
    const float* Li = (const float*)d_in[2];
    const float* Pr = (const float*)d_in[3];
    const float* Pi = (const float*)d_in[4];
    const float* Br = (const float*)d_in[5];
    const float* Bi = (const float*)d_in[6];
    const float* Cr = (const float*)d_in[7];
    const float* Ci = (const float*)d_in[8];
    const float* ld = (const float*)d_in[9];
    const float* Dv = (const float*)d_in[10];
    float* out = (float*)d_out;

    const size_t UT_BYTES = (size_t)NBATCH * HCH * LSEQ * sizeof(float);   // 32 MB
    const size_t KF_BYTES = (size_t)HCH * 2049 * sizeof(float2);           // 8.4 MB
    const int fast = (ws_size >= UT_BYTES + KF_BYTES) ? 1 : 0;

    float*  ut;
    float2* Kf;
    if (fast) { ut = (float*)d_ws; Kf = (float2*)((char*)d_ws + UT_BYTES); }
    else      { ut = (float*)d_ws; Kf = (float2*)d_ws; }   // slow path: Kf only

    // K1: conv-kernel spectrum per channel
    hipLaunchKernelGGL(s4_kf_kernel, dim3(HCH), dim3(256), 0, stream,
                       Lr, Li, Pr, Pi, Br, Bi, Cr, Ci, ld, Kf);
    if (fast) {
        // K2: u (B,L,H) -> ut (B,H,L)
        hipLaunchKernelGGL(transpose_kernel, dim3(HCH / 32, LSEQ / 32, NBATCH),
                           dim3(256), 0, stream, u, ut, LSEQ, HCH);
    }
    // K3: FFT convolution per (b,h) row (in place on ut if fast)
    hipLaunchKernelGGL(s4_conv_kernel, dim3(NBATCH * HCH), dim3(256), 0, stream,
                       u, fast ? ut : nullptr, Kf, Dv, out, fast);
    if (fast) {
        // K4: ut (B,H,L) -> out (B,L,H)
        hipLaunchKernelGGL(transpose_kernel, dim3(LSEQ / 32, HCH / 32, NBATCH),
                           dim3(256), 0, stream, ut, out, HCH, LSEQ);
    }
}

// Round 2
// 139.026 us; speedup vs baseline: 1.2623x; 1.2623x over previous
//
#include <hip/hip_runtime.h>
#include <math.h>

// Problem constants
#define LSEQ 2048          // sequence length L (also FFT size N)
#define HCH  512           // channels H
#define NST  64            // state size N
#define NBATCH 8           // batch B

// Padded LDS layout: phys(i) = i + i/8  -> kills bank conflicts on the
// per-thread 8-element strided FFT writes while keeping contiguous-lane
// accesses conflict-free. Max phys(2047) = 2302 < 2304.
#define PHYS(i) ((i) + ((i) >> 3))
#define LDSN 2304

__device__ __forceinline__ float2 cmul(float2 a, float2 b) {
    return make_float2(a.x * b.x - a.y * b.y, a.x * b.y + a.y * b.x);
}
__device__ __forceinline__ float2 cadd(float2 a, float2 b) { return make_float2(a.x + b.x, a.y + b.y); }
__device__ __forceinline__ float2 csub(float2 a, float2 b) { return make_float2(a.x - b.x, a.y - b.y); }
__device__ __forceinline__ float2 csq(float2 a) { return make_float2(a.x * a.x - a.y * a.y, 2.f * a.x * a.y); }
// multiply by -i (forward) / +i (inverse)
template<int INV>
__device__ __forceinline__ float2 rot90(float2 a) {
    return INV ? make_float2(-a.y, a.x) : make_float2(a.y, -a.x);
}

// ---------------------------------------------------------------------------
// One register-blocked radix-8 Stockham pass (fuses radix-2 stages
// STAGE, STAGE+1, STAGE+2). 256 threads, one 8-butterfly per thread.
// Derived by composing the (verified) radix-2 stage mapping:
//   reads  src[tid + 256*m], pairs (m, m+4) at level 1
//   writes dst[G + Ns*m],  G = ((tid>>STAGE)<<(STAGE+3)) + (tid & (Ns-1))
// ---------------------------------------------------------------------------
template<int INV, int STAGE>
__device__ __forceinline__ void radix8_pass(const float2* __restrict__ src,
                                            float2* __restrict__ dst, int tid)
{
    const int Ns  = 1 << STAGE;
    const int lam = tid & (Ns - 1);
    const int G   = ((tid >> STAGE) << (STAGE + 3)) + lam;

    float2 x0 = src[PHYS(tid)];
    float2 x1 = src[PHYS(tid + 256)];
    float2 x2 = src[PHYS(tid + 512)];
    float2 x3 = src[PHYS(tid + 768)];
    float2 x4 = src[PHYS(tid + 1024)];
    float2 x5 = src[PHYS(tid + 1280)];
    float2 x6 = src[PHYS(tid + 1536)];
    float2 x7 = src[PHYS(tid + 1792)];

    const float SGN = INV ? 1.f : -1.f;
    float sn, cs;
    __sincosf(SGN * ((float)M_PI / (float)(4 * Ns)) * (float)lam, &sn, &cs);
    const float2 T3 = make_float2(cs, sn);        // e^{SGN*i*pi*lam/(4Ns)}
    const float2 T2 = csq(T3);                    // e^{SGN*i*pi*lam/(2Ns)}
    const float2 T1 = csq(T2);                    // e^{SGN*i*pi*lam/Ns}
    const float r2 = 0.70710678118f;
    const float2 U = cmul(T3, make_float2(r2, SGN * r2));   // T3 * e^{SGN*i*pi/4}

    float2 t;
    // level 1 (stage STAGE): pairs (m, m+4), twiddle T1
    t = cmul(T1, x4); float2 a0 = cadd(x0, t), a4 = csub(x0, t);
    t = cmul(T1, x5); float2 a1 = cadd(x1, t), a5 = csub(x1, t);
    t = cmul(T1, x6); float2 a2 = cadd(x2, t), a6 = csub(x2, t);
    t = cmul(T1, x7); float2 a3 = cadd(x3, t), a7 = csub(x3, t);
    // level 2 (stage STAGE+1): (0,2),(1,3) tw T2 ; (4,6),(5,7) tw rot(T2)
    t = cmul(T2, a2);            float2 b0 = cadd(a0, t), b2 = csub(a0, t);
    t = cmul(T2, a3);            float2 b1 = cadd(a1, t), b3 = csub(a1, t);
    t = rot90<INV>(cmul(T2, a6)); float2 b4 = cadd(a4, t), b6 = csub(a4, t);
    t = rot90<INV>(cmul(T2, a7)); float2 b5 = cadd(a5, t), b7 = csub(a5, t);
    // level 3 (stage STAGE+2) + scatter
    t = cmul(T3, b1);            dst[PHYS(G)]          = cadd(b0, t); dst[PHYS(G + 4 * Ns)] = csub(b0, t);
    t = rot90<INV>(cmul(T3, b3)); dst[PHYS(G + 2 * Ns)] = cadd(b2, t); dst[PHYS(G + 6 * Ns)] = csub(b2, t);
    t = cmul(U, b5);             dst[PHYS(G + Ns)]     = cadd(b4, t); dst[PHYS(G + 5 * Ns)] = csub(b4, t);
    t = rot90<INV>(cmul(U, b7)); dst[PHYS(G + 3 * Ns)] = cadd(b6, t); dst[PHYS(G + 7 * Ns)] = csub(b6, t);
}

// ---------------------------------------------------------------------------
// 2048-pt complex FFT: radix-8 passes s=0,3,6 then radix-4 pass s=9.
// numpy convention forward (e^{-2pi i nk/N}); INV=1 unnormalized inverse.
// Result always ends in bufA (the first argument).
// ---------------------------------------------------------------------------
template<int INV>
__device__ float2* fft2048(float2* bufA, float2* bufB)
{
    const int tid = threadIdx.x;
    __syncthreads();
    radix8_pass<INV, 0>(bufA, bufB, tid);
    __syncthreads();
    radix8_pass<INV, 3>(bufB, bufA, tid);
    __syncthreads();
    radix8_pass<INV, 6>(bufA, bufB, tid);
    __syncthreads();
    // radix-4 (stages 9,10): Ns=512, two butterflies/thread, bufB -> bufA
    const float SGN = INV ? 1.f : -1.f;
#pragma unroll
    for (int q = 0; q < 2; ++q) {
        const int j = tid + (q << 8);              // 0..511
        float2 A  = bufB[PHYS(j)];
        float2 C  = bufB[PHYS(j + 512)];
        float2 B  = bufB[PHYS(j + 1024)];
        float2 Dd = bufB[PHYS(j + 1536)];
        float sn, cs;
        __sincosf(SGN * ((float)M_PI / 1024.f) * (float)j, &sn, &cs);
        const float2 v = make_float2(cs, sn);      // e^{SGN*i*pi*j/1024}
        const float2 w = csq(v);                   // e^{SGN*i*pi*j/512}
        float2 t = cmul(w, B);  float2 m1 = cadd(A, t), m2 = csub(A, t);
        t = cmul(w, Dd);        float2 m3 = cadd(C, t), m4 = csub(C, t);
        const float2 t3 = cmul(v, m3);
        const float2 t4 = rot90<INV>(cmul(v, m4));
        bufA[PHYS(j)]        = cadd(m1, t3);
        bufA[PHYS(j + 1024)] = csub(m1, t3);
        bufA[PHYS(j + 512)]  = cadd(m2, t4);
        bufA[PHYS(j + 1536)] = csub(m2, t4);
    }
    __syncthreads();
    return bufA;
}

// ---------------------------------------------------------------------------
// Kernel 1: per channel h, at_roots (Cauchy) -> ifft -> K -> Kf = rfft4096(K)
// ---------------------------------------------------------------------------
__global__ __launch_bounds__(256, 4)
void s4_kf_kernel(const float* __restrict__ Lr, const float* __restrict__ Li,
                  const float* __restrict__ Pr, const float* __restrict__ Pi,
                  const float* __restrict__ Br, const float* __restrict__ Bi,
                  const float* __restrict__ Cr, const float* __restrict__ Ci,
                  const float* __restrict__ log_dt, float2* __restrict__ Kf)
{
    __shared__ float2 bufA[LDSN];
    __shared__ float2 bufB[LDSN];
    __shared__ float  lamRe[NST], lamIm[NST], q1s[NST];
    __shared__ float2 w00s[NST], w01s[NST], q0s[NST];

    const int h   = blockIdx.x;
    const int tid = threadIdx.x;

    if (tid < NST) {
        const int n = tid;
        const float pr = Pr[n], pi = Pi[n], br = Br[n], bi = Bi[n];
        lamRe[n] = Lr[n];
        lamIm[n] = Li[n];
        q0s[n] = make_float2(pr * br + pi * bi, pr * bi - pi * br);
        q1s[n] = pr * pr + pi * pi;
        const float cr = Cr[h * NST + n], ci = Ci[h * NST + n];
        w00s[n] = make_float2(cr * br + ci * bi, cr * bi - ci * br);
        w01s[n] = make_float2(cr * pr + ci * pi, cr * pi - ci * pr);
    }
    __syncthreads();

    const float dt = expf(log_dt[h]);
    const float a  = 2.0f / dt;

    for (int q = 0; q < 8; ++q) {
        const int l = tid + (q << 8);
        const float t   = tanf((float)M_PI * (float)l * (1.0f / 2048.0f));
        const float at_ = a * t;
        float k00r = 0.f, k00i = 0.f, k01r = 0.f, k01i = 0.f;
        float k10r = 0.f, k10i = 0.f, k11r = 0.f, k11i = 0.f;
#pragma unroll 8
        for (int n = 0; n < NST; ++n) {
            const float x = -lamRe[n];
            const float y = at_ - lamIm[n];
            const float inv = __builtin_amdgcn_rcpf(x * x + y * y);
            const float rr = x * inv, ri = -y * inv;
            float2 w;
            w = w00s[n]; k00r += w.x * rr - w.y * ri; k00i += w.x * ri + w.y * rr;
            w = w01s[n]; k01r += w.x * rr - w.y * ri; k01i += w.x * ri + w.y * rr;
            w = q0s[n];  k10r += w.x * rr - w.y * ri; k10i += w.x * ri + w.y * rr;
            const float q1 = q1s[n]; k11r += q1 * rr; k11i += q1 * ri;
        }
        const float dr = 1.0f + k11r, di = k11i;
        const float dinv = __builtin_amdgcn_rcpf(dr * dr + di * di);
        const float pr_ = k01r * k10r - k01i * k10i;
        const float pi_ = k01r * k10i + k01i * k10r;
        const float qr = (pr_ * dr + pi_ * di) * dinv;
        const float qi = (pi_ * dr - pr_ * di) * dinv;
        const float sr = k00r - qr, si = k00i - qi;
        bufA[PHYS(l)] = make_float2(sr - t * si, si + t * sr);
    }

    // K = Re(ifft(at)) / 2048   (result in bufA)
    float2* Kt = fft2048<1>(bufA, bufB);

    // pack z[n] = K[2n] + i K[2n+1] -> bufB, zero tail
    const float sc = 1.0f / 2048.0f;
    for (int n = tid; n < 1024; n += 256)
        bufB[PHYS(n)] = make_float2(Kt[PHYS(2 * n)].x * sc, Kt[PHYS(2 * n + 1)].x * sc);
    for (int n = 1024 + tid; n < 2048; n += 256)
        bufB[PHYS(n)] = make_float2(0.f, 0.f);

    float2* Z = fft2048<0>(bufB, bufA);   // result in bufB

    // unpack rfft-4096: Kf[k] = Ze + e^{-2pi i k/4096} Zo
    float2* __restrict__ out = Kf + (size_t)h * 2049;
    for (int k = tid; k < 1024; k += 256) {
        const float2 Zk = Z[PHYS(k)];
        const float2 Zm = Z[PHYS((2048 - k) & 2047)];
        const float zer = 0.5f * (Zk.x + Zm.x), zei = 0.5f * (Zk.y - Zm.y);
        const float zdr = Zk.x - Zm.x,         zdi = Zk.y + Zm.y;
        const float zor = 0.5f * zdi,          zoi = -0.5f * zdr;
        float s, c;
        __sincosf(-(float)M_PI * (float)k * (1.0f / 2048.0f), &s, &c);
        const float txr = c * zor - s * zoi;
        const float txi = c * zoi + s * zor;
        out[k] = make_float2(zer + txr, zei + txi);
        if (k > 0) {
            out[2048 - k] = make_float2(zer - txr, txi - zei);
        } else {
            out[2048] = make_float2(Zk.x - Zk.y, 0.f);
        }
    }
    if (tid == 0) {
        const float2 z = Z[PHYS(1024)];
        out[1024] = make_float2(z.x, -z.y);
    }
}

// ---------------------------------------------------------------------------
// Kernel 3: per (b,h) row: rfft4096(x) -> *Kf -> irfft4096 -> + D*x.
// ---------------------------------------------------------------------------
__global__ __launch_bounds__(256, 4)
void s4_conv_kernel(const float* __restrict__ u, float* ws_rows,
                    const float2* __restrict__ Kf, const float* __restrict__ Dv,
                    float* __restrict__ out, int fastpath)
{
    __shared__ float2 bufA[LDSN];
    __shared__ float2 bufB[LDSN];
    __shared__ float2 yfN;   // Yf[2048]

    const int bh  = blockIdx.x;
    const int b   = bh >> 9;
    const int h   = bh & 511;
    const int tid = threadIdx.x;

    // pack x: z[n] = x[2n] + i x[2n+1] -> bufA, zero tail
    if (fastpath) {
        const float2* rowv = (const float2*)(ws_rows + (size_t)bh * LSEQ);
        for (int n = tid; n < 1024; n += 256) bufA[PHYS(n)] = rowv[n];
    } else {
        const float* ub = u + (size_t)b * LSEQ * HCH + h;
        for (int n = tid; n < 1024; n += 256)
            bufA[PHYS(n)] = make_float2(ub[(size_t)(2 * n) * HCH],
                                        ub[(size_t)(2 * n + 1) * HCH]);
    }
    for (int n = 1024 + tid; n < 2048; n += 256) bufA[PHYS(n)] = make_float2(0.f, 0.f);

    float2* Z  = fft2048<0>(bufA, bufB);   // Z = bufA
    float2* NB = bufB;                     // dead buffer
    const float2* __restrict__ kf = Kf + (size_t)h * 2049;

    // Yf[k] = Xf[k] * Kf[k]  into NB
    for (int k = tid; k < 1024; k += 256) {
        const float2 Zk = Z[PHYS(k)];
        const float2 Zm = Z[PHYS((2048 - k) & 2047)];
        const float zer = 0.5f * (Zk.x + Zm.x), zei = 0.5f * (Zk.y - Zm.y);
        const float zdr = Zk.x - Zm.x,          zdi = Zk.y + Zm.y;
        const float zor = 0.5f * zdi,           zoi = -0.5f * zdr;
        float s, c;
        __sincosf(-(float)M_PI * (float)k * (1.0f / 2048.0f), &s, &c);
        const float txr = c * zor - s * zoi;
        const float txi = c * zoi + s * zor;
        const float xr = zer + txr, xi = zei + txi;        // Xf[k]
        const float2 kk = kf[k];
        NB[PHYS(k)] = make_float2(xr * kk.x - xi * kk.y, xr * kk.y + xi * kk.x);
        if (k > 0) {
            const float mr = zer - txr, mi = txi - zei;    // Xf[2048-k]
            const float2 km = kf[2048 - k];
            NB[PHYS(2048 - k)] = make_float2(mr * km.x - mi * km.y,
                                             mr * km.y + mi * km.x);
        } else {
            const float x2048 = Zk.x - Zk.y;               // Xf[2048] (real)
            const float2 k2 = kf[2048];
            yfN = make_float2(x2048 * k2.x, x2048 * k2.y);
        }
    }
    if (tid == 0) {
        const float2 z  = Z[PHYS(1024)];
        const float2 kk = kf[1024];
        NB[PHYS(1024)] = make_float2(z.x * kk.x + z.y * kk.y,
                                     z.x * kk.y - z.y * kk.x);
    }
    __syncthreads();

    // W[k] = Ye[k] + i*Yo[k] into bufA (Z dead)
    for (int k = tid; k < 1024; k += 256) {
        const float2 Yk = NB[PHYS(k)];
        const float2 Ym = (k == 0) ? yfN : NB[PHYS(2048 - k)];
        const float yer = 0.5f * (Yk.x + Ym.x), yei = 0.5f * (Yk.y - Ym.y);
        const float ydr = Yk.x - Ym.x,          ydi = Yk.y + Ym.y;
        float s, c;
        __sincosf((float)M_PI * (float)k * (1.0f / 2048.0f), &s, &c);
        const float yor = 0.5f * (c * ydr - s * ydi);
        const float yoi = 0.5f * (c * ydi + s * ydr);
        bufA[PHYS(k)] = make_float2(yer - yoi, yei + yor);
        if (k > 0) {
            const float yer2 = 0.5f * (Ym.x + Yk.x), yei2 = 0.5f * (Ym.y - Yk.y);
            const float ydr2 = Ym.x - Yk.x,          ydi2 = Ym.y + Yk.y;
            const float yor2 = 0.5f * (-c * ydr2 - s * ydi2);
            const float yoi2 = 0.5f * (-c * ydi2 + s * ydr2);
            bufA[PHYS(2048 - k)] = make_float2(yer2 - yoi2, yei2 + yor2);
        }
    }
    if (tid == 0) {
        const float2 Y = NB[PHYS(1024)];
        bufA[PHYS(1024)] = make_float2(Y.x, -Y.y);
    }

    float2* w = fft2048<1>(bufA, bufB);    // result in bufA
    const float Dh = Dv[h];
    const float sc = 1.0f / 2048.0f;
    if (fastpath) {
        float2* rowv = (float2*)(ws_rows + (size_t)bh * LSEQ);
        for (int n = tid; n < 1024; n += 256) {
            const float2 wv = w[PHYS(n)];
            const float2 xv = rowv[n];
            rowv[n] = make_float2(wv.x * sc + Dh * xv.x,
                                  wv.y * sc + Dh * xv.y);
        }
    } else {
        const float* ub = u + (size_t)b * LSEQ * HCH + h;
        float* ob = out + (size_t)b * LSEQ * HCH + h;
        for (int n = tid; n < 1024; n += 256) {
            const float2 wv = w[PHYS(n)];
            ob[(size_t)(2 * n) * HCH]     = wv.x * sc + Dh * ub[(size_t)(2 * n) * HCH];
            ob[(size_t)(2 * n + 1) * HCH] = wv.y * sc + Dh * ub[(size_t)(2 * n + 1) * HCH];
        }
    }
}

// ---------------------------------------------------------------------------
// Batched 2D transpose: in (B, rows, cols) -> out (B, cols, rows)
// ---------------------------------------------------------------------------
__global__ __launch_bounds__(256)
void transpose_kernel(const float* __restrict__ in, float* __restrict__ out,
                      int rows, int cols)
{
    __shared__ float tile[32][33];
    const int b  = blockIdx.z;
    const int r0 = blockIdx.y << 5;
    const int c0 = blockIdx.x << 5;
    const size_t base = (size_t)b * rows * cols;
    const int tx = threadIdx.x & 31;
    const int ty = threadIdx.x >> 5;
#pragma unroll
    for (int i = 0; i < 32; i += 8)
        tile[ty + i][tx] = in[base + (size_t)(r0 + ty + i) * cols + (c0 + tx)];
    __syncthreads();
#pragma unroll
    for (int i = 0; i < 32; i += 8)
        out[base + (size_t)(c0 + ty + i) * rows + (r0 + tx)] = tile[tx][ty + i];
}

// ---------------------------------------------------------------------------
extern "C" void kernel_launch(void* const* d_in, const int* in_sizes, int n_in,
                              void* d_out, int out_size, void* d_ws, size_t ws_size,
                              hipStream_t stream)
{
    (void)in_sizes; (void)n_in; (void)out_size;
    const float* u  = (const float*)d_in[0];
    const float* Lr = (const float*)d_in[1];
    const float* Li = (const float*)d_in[2];
    const float* Pr = (const float*)d_in[3];
    const float* Pi = (const float*)d_in[4];
    const float* Br = (const float*)d_in[5];
    const float* Bi = (const float*)d_in[6];
    const float* Cr = (const float*)d_in[7];
    const float* Ci = (const float*)d_in[8];
    const float* ld = (const float*)d_in[9];
    const float* Dv = (const float*)d_in[10];
    float* out = (float*)d_out;

    const size_t UT_BYTES = (size_t)NBATCH * HCH * LSEQ * sizeof(float);   // 32 MB
    const size_t KF_BYTES = (size_t)HCH * 2049 * sizeof(float2);           // 8.4 MB
    const int fast = (ws_size >= UT_BYTES + KF_BYTES) ? 1 : 0;

    float*  ut;
    float2* Kf;
    if (fast) { ut = (float*)d_ws; Kf = (float2*)((char*)d_ws + UT_BYTES); }
    else      { ut = (float*)d_ws; Kf = (float2*)d_ws; }

    hipLaunchKernelGGL(s4_kf_kernel, dim3(HCH), dim3(256), 0, stream,
                       Lr, Li, Pr, Pi, Br, Bi, Cr, Ci, ld, Kf);
    if (fast) {
        hipLaunchKernelGGL(transpose_kernel, dim3(HCH / 32, LSEQ / 32, NBATCH),
                           dim3(256), 0, stream, u, ut, LSEQ, HCH);
    }
    hipLaunchKernelGGL(s4_conv_kernel, dim3(NBATCH * HCH), dim3(256), 0, stream,
                       u, fast ? ut : nullptr, Kf, Dv, out, fast);
    if (fast) {
        hipLaunchKernelGGL(transpose_kernel, dim3(LSEQ / 32, HCH / 32, NBATCH),
                           dim3(256), 0, stream, ut, out, HCH, LSEQ);
    }
}

// Round 5
// 134.211 us; speedup vs baseline: 1.3076x; 1.0359x over previous
//
#include <hip/hip_runtime.h>
#include <math.h>

#define LSEQ 2048
#define HCH  512
#define NST  64
#define NBATCH 8
#define PIf 3.14159265358979f

// Padded LDS layout: phys(i) = i + i/8 (verified r2)
#define PHYS(i) ((i) + ((i) >> 3))
#define LDSN 2304

__device__ __forceinline__ float2 cmul(float2 a, float2 b) {
    return make_float2(a.x * b.x - a.y * b.y, a.x * b.y + a.y * b.x);
}
__device__ __forceinline__ float2 cadd(float2 a, float2 b) { return make_float2(a.x + b.x, a.y + b.y); }
__device__ __forceinline__ float2 csub(float2 a, float2 b) { return make_float2(a.x - b.x, a.y - b.y); }
__device__ __forceinline__ float2 csq(float2 a) { return make_float2(a.x * a.x - a.y * a.y, 2.f * a.x * a.y); }
template<int INV>
__device__ __forceinline__ float2 rot90(float2 a) {
    return INV ? make_float2(-a.y, a.x) : make_float2(a.y, -a.x);
}

// ---------------------------------------------------------------------------
// Radix-8 Stockham pass, ping-pong (VERBATIM r2 — verified passing).
// ---------------------------------------------------------------------------
template<int INV, int STAGE>
__device__ __forceinline__ void radix8_pass(const float2* __restrict__ src,
                                            float2* __restrict__ dst, int tid)
{
    const int Ns  = 1 << STAGE;
    const int lam = tid & (Ns - 1);
    const int G   = ((tid >> STAGE) << (STAGE + 3)) + lam;

    float2 x0 = src[PHYS(tid)];
    float2 x1 = src[PHYS(tid + 256)];
    float2 x2 = src[PHYS(tid + 512)];
    float2 x3 = src[PHYS(tid + 768)];
    float2 x4 = src[PHYS(tid + 1024)];
    float2 x5 = src[PHYS(tid + 1280)];
    float2 x6 = src[PHYS(tid + 1536)];
    float2 x7 = src[PHYS(tid + 1792)];

    const float SGN = INV ? 1.f : -1.f;
    float sn, cs;
    __sincosf(SGN * (PIf / (float)(4 * Ns)) * (float)lam, &sn, &cs);
    const float2 T3 = make_float2(cs, sn);
    const float2 T2 = csq(T3);
    const float2 T1 = csq(T2);
    const float r2 = 0.70710678118f;
    const float2 U = cmul(T3, make_float2(r2, SGN * r2));

    float2 t;
    t = cmul(T1, x4); float2 a0 = cadd(x0, t), a4 = csub(x0, t);
    t = cmul(T1, x5); float2 a1 = cadd(x1, t), a5 = csub(x1, t);
    t = cmul(T1, x6); float2 a2 = cadd(x2, t), a6 = csub(x2, t);
    t = cmul(T1, x7); float2 a3 = cadd(x3, t), a7 = csub(x3, t);
    t = cmul(T2, a2);             float2 b0 = cadd(a0, t), b2 = csub(a0, t);
    t = cmul(T2, a3);             float2 b1 = cadd(a1, t), b3 = csub(a1, t);
    t = rot90<INV>(cmul(T2, a6)); float2 b4 = cadd(a4, t), b6 = csub(a4, t);
    t = rot90<INV>(cmul(T2, a7)); float2 b5 = cadd(a5, t), b7 = csub(a5, t);
    t = cmul(T3, b1);             dst[PHYS(G)]          = cadd(b0, t); dst[PHYS(G + 4 * Ns)] = csub(b0, t);
    t = rot90<INV>(cmul(T3, b3)); dst[PHYS(G + 2 * Ns)] = cadd(b2, t); dst[PHYS(G + 6 * Ns)] = csub(b2, t);
    t = cmul(U, b5);              dst[PHYS(G + Ns)]     = cadd(b4, t); dst[PHYS(G + 5 * Ns)] = csub(b4, t);
    t = rot90<INV>(cmul(U, b7));  dst[PHYS(G + 3 * Ns)] = cadd(b6, t); dst[PHYS(G + 7 * Ns)] = csub(b6, t);
}

// ---------------------------------------------------------------------------
// 2048-pt FFT, double-buffer ping-pong (VERBATIM r2). Result in bufA.
// ---------------------------------------------------------------------------
template<int INV>
__device__ float2* fft2048(float2* bufA, float2* bufB)
{
    const int tid = threadIdx.x;
    __syncthreads();
    radix8_pass<INV, 0>(bufA, bufB, tid);
    __syncthreads();
    radix8_pass<INV, 3>(bufB, bufA, tid);
    __syncthreads();
    radix8_pass<INV, 6>(bufA, bufB, tid);
    __syncthreads();
    const float SGN = INV ? 1.f : -1.f;
#pragma unroll
    for (int q = 0; q < 2; ++q) {
        const int j = tid + (q << 8);
        float2 A  = bufB[PHYS(j)];
        float2 C  = bufB[PHYS(j + 512)];
        float2 B  = bufB[PHYS(j + 1024)];
        float2 Dd = bufB[PHYS(j + 1536)];
        float sn, cs;
        __sincosf(SGN * (PIf / 1024.f) * (float)j, &sn, &cs);
        const float2 v = make_float2(cs, sn);
        const float2 w = csq(v);
        float2 t = cmul(w, B);  float2 m1 = cadd(A, t), m2 = csub(A, t);
        t = cmul(w, Dd);        float2 m3 = cadd(C, t), m4 = csub(C, t);
        const float2 t3 = cmul(v, m3);
        const float2 t4 = rot90<INV>(cmul(v, m4));
        bufA[PHYS(j)]        = cadd(m1, t3);
        bufA[PHYS(j + 1024)] = csub(m1, t3);
        bufA[PHYS(j + 512)]  = cadd(m2, t4);
        bufA[PHYS(j + 1536)] = csub(m2, t4);
    }
    __syncthreads();
    return bufA;
}

// ---------------------------------------------------------------------------
// NEW (the single bisect variable): Cauchy at_roots split out.
// Block = (h, quarter segment), 2 l-points/thread. Body = r2 verbatim.
// ---------------------------------------------------------------------------
__global__ __launch_bounds__(256)
void s4_cauchy_kernel(const float* __restrict__ Lr, const float* __restrict__ Li,
                      const float* __restrict__ Pr, const float* __restrict__ Pi,
                      const float* __restrict__ Br, const float* __restrict__ Bi,
                      const float* __restrict__ Cr, const float* __restrict__ Ci,
                      const float* __restrict__ log_dt, float2* __restrict__ at_out)
{
    __shared__ float  lamRe[NST], lamIm[NST], q1s[NST];
    __shared__ float2 w00s[NST], w01s[NST], q0s[NST];

    const int h   = blockIdx.x >> 2;
    const int seg = blockIdx.x & 3;
    const int tid = threadIdx.x;

    if (tid < NST) {
        const int n = tid;
        const float pr = Pr[n], pi = Pi[n], br = Br[n], bi = Bi[n];
        lamRe[n] = Lr[n];
        lamIm[n] = Li[n];
        q0s[n] = make_float2(pr * br + pi * bi, pr * bi - pi * br);
        q1s[n] = pr * pr + pi * pi;
        const float cr = Cr[h * NST + n], ci = Ci[h * NST + n];
        w00s[n] = make_float2(cr * br + ci * bi, cr * bi - ci * br);
        w01s[n] = make_float2(cr * pr + ci * pi, cr * pi - ci * pr);
    }
    __syncthreads();

    const float dt = expf(log_dt[h]);
    const float a  = 2.0f / dt;
    float2* __restrict__ row = at_out + (size_t)h * 2048;

    for (int q = 0; q < 2; ++q) {
        const int l = (seg << 9) + (q << 8) + tid;
        const float t   = tanf(PIf * (float)l * (1.0f / 2048.0f));
        const float at_ = a * t;
        float k00r = 0.f, k00i = 0.f, k01r = 0.f, k01i = 0.f;
        float k10r = 0.f, k10i = 0.f, k11r = 0.f, k11i = 0.f;
#pragma unroll 8
        for (int n = 0; n < NST; ++n) {
            const float x = -lamRe[n];
            const float y = at_ - lamIm[n];
            const float inv = __builtin_amdgcn_rcpf(x * x + y * y);
            const float rr = x * inv, ri = -y * inv;
            float2 w;
            w = w00s[n]; k00r += w.x * rr - w.y * ri; k00i += w.x * ri + w.y * rr;
            w = w01s[n]; k01r += w.x * rr - w.y * ri; k01i += w.x * ri + w.y * rr;
            w = q0s[n];  k10r += w.x * rr - w.y * ri; k10i += w.x * ri + w.y * rr;
            const float q1 = q1s[n]; k11r += q1 * rr; k11i += q1 * ri;
        }
        const float dr = 1.0f + k11r, di = k11i;
        const float dinv = __builtin_amdgcn_rcpf(dr * dr + di * di);
        const float pr_ = k01r * k10r - k01i * k10i;
        const float pi_ = k01r * k10i + k01i * k10r;
        const float qr = (pr_ * dr + pi_ * di) * dinv;
        const float qi = (pi_ * dr - pr_ * di) * dinv;
        const float sr = k00r - qr, si = k00i - qi;
        row[l] = make_float2(sr - t * si, si + t * sr);
    }
}

// ---------------------------------------------------------------------------
// kf kernel (r2 verbatim, Cauchy replaced by a global load of at).
// ---------------------------------------------------------------------------
__global__ __launch_bounds__(256, 4)
void s4_kf_kernel(const float2* __restrict__ at_in, float2* __restrict__ Kf)
{
    __shared__ float2 bufA[LDSN];
    __shared__ float2 bufB[LDSN];

    const int h   = blockIdx.x;
    const int tid = threadIdx.x;
    const float2* __restrict__ at = at_in + (size_t)h * 2048;

    for (int q = 0; q < 8; ++q) {
        const int l = tid + (q << 8);
        bufA[PHYS(l)] = at[l];
    }

    // K = Re(ifft(at)) / 2048   (result in bufA)
    float2* Kt = fft2048<1>(bufA, bufB);

    // pack z[n] = (K[2n] + i K[2n+1]) / 2048 -> bufB, zero tail
    const float sc = 1.0f / 2048.0f;
    for (int n = tid; n < 1024; n += 256)
        bufB[PHYS(n)] = make_float2(Kt[PHYS(2 * n)].x * sc, Kt[PHYS(2 * n + 1)].x * sc);
    for (int n = 1024 + tid; n < 2048; n += 256)
        bufB[PHYS(n)] = make_float2(0.f, 0.f);

    float2* Z = fft2048<0>(bufB, bufA);   // result in bufB

    float2* __restrict__ out = Kf + (size_t)h * 2049;
    for (int k = tid; k < 1024; k += 256) {
        const float2 Zk = Z[PHYS(k)];
        const float2 Zm = Z[PHYS((2048 - k) & 2047)];
        const float zer = 0.5f * (Zk.x + Zm.x), zei = 0.5f * (Zk.y - Zm.y);
        const float zdr = Zk.x - Zm.x,         zdi = Zk.y + Zm.y;
        const float zor = 0.5f * zdi,          zoi = -0.5f * zdr;
        float s, c;
        __sincosf(-PIf * (float)k * (1.0f / 2048.0f), &s, &c);
        const float txr = c * zor - s * zoi;
        const float txi = c * zoi + s * zor;
        out[k] = make_float2(zer + txr, zei + txi);
        if (k > 0) {
            out[2048 - k] = make_float2(zer - txr, txi - zei);
        } else {
            out[2048] = make_float2(Zk.x - Zk.y, 0.f);
        }
    }
    if (tid == 0) {
        const float2 z = Z[PHYS(1024)];
        out[1024] = make_float2(z.x, -z.y);
    }
}

// ---------------------------------------------------------------------------
// conv kernel (VERBATIM r2).
// ---------------------------------------------------------------------------
__global__ __launch_bounds__(256, 4)
void s4_conv_kernel(const float* __restrict__ u, float* ws_rows,
                    const float2* __restrict__ Kf, const float* __restrict__ Dv,
                    float* __restrict__ out, int fastpath)
{
    __shared__ float2 bufA[LDSN];
    __shared__ float2 bufB[LDSN];
    __shared__ float2 yfN;

    const int bh  = blockIdx.x;
    const int b   = bh >> 9;
    const int h   = bh & 511;
    const int tid = threadIdx.x;

    if (fastpath) {
        const float2* rowv = (const float2*)(ws_rows + (size_t)bh * LSEQ);
        for (int n = tid; n < 1024; n += 256) bufA[PHYS(n)] = rowv[n];
    } else {
        const float* ub = u + (size_t)b * LSEQ * HCH + h;
        for (int n = tid; n < 1024; n += 256)
            bufA[PHYS(n)] = make_float2(ub[(size_t)(2 * n) * HCH],
                                        ub[(size_t)(2 * n + 1) * HCH]);
    }
    for (int n = 1024 + tid; n < 2048; n += 256) bufA[PHYS(n)] = make_float2(0.f, 0.f);

    float2* Z  = fft2048<0>(bufA, bufB);   // Z = bufA
    float2* NB = bufB;
    const float2* __restrict__ kf = Kf + (size_t)h * 2049;

    for (int k = tid; k < 1024; k += 256) {
        const float2 Zk = Z[PHYS(k)];
        const float2 Zm = Z[PHYS((2048 - k) & 2047)];
        const float zer = 0.5f * (Zk.x + Zm.x), zei = 0.5f * (Zk.y - Zm.y);
        const float zdr = Zk.x - Zm.x,          zdi = Zk.y + Zm.y;
        const float zor = 0.5f * zdi,           zoi = -0.5f * zdr;
        float s, c;
        __sincosf(-PIf * (float)k * (1.0f / 2048.0f), &s, &c);
        const float txr = c * zor - s * zoi;
        const float txi = c * zoi + s * zor;
        const float xr = zer + txr, xi = zei + txi;
        const float2 kk = kf[k];
        NB[PHYS(k)] = make_float2(xr * kk.x - xi * kk.y, xr * kk.y + xi * kk.x);
        if (k > 0) {
            const float mr = zer - txr, mi = txi - zei;
            const float2 km = kf[2048 - k];
            NB[PHYS(2048 - k)] = make_float2(mr * km.x - mi * km.y,
                                             mr * km.y + mi * km.x);
        } else {
            const float x2048 = Zk.x - Zk.y;
            const float2 k2 = kf[2048];
            yfN = make_float2(x2048 * k2.x, x2048 * k2.y);
        }
    }
    if (tid == 0) {
        const float2 z  = Z[PHYS(1024)];
        const float2 kk = kf[1024];
        NB[PHYS(1024)] = make_float2(z.x * kk.x + z.y * kk.y,
                                     z.x * kk.y - z.y * kk.x);
    }
    __syncthreads();

    for (int k = tid; k < 1024; k += 256) {
        const float2 Yk = NB[PHYS(k)];
        const float2 Ym = (k == 0) ? yfN : NB[PHYS(2048 - k)];
        const float yer = 0.5f * (Yk.x + Ym.x), yei = 0.5f * (Yk.y - Ym.y);
        const float ydr = Yk.x - Ym.x,          ydi = Yk.y + Ym.y;
        float s, c;
        __sincosf(PIf * (float)k * (1.0f / 2048.0f), &s, &c);
        const float yor = 0.5f * (c * ydr - s * ydi);
        const float yoi = 0.5f * (c * ydi + s * ydr);
        bufA[PHYS(k)] = make_float2(yer - yoi, yei + yor);
        if (k > 0) {
            const float yer2 = 0.5f * (Ym.x + Yk.x), yei2 = 0.5f * (Ym.y - Yk.y);
            const float ydr2 = Ym.x - Yk.x,          ydi2 = Ym.y + Yk.y;
            const float yor2 = 0.5f * (-c * ydr2 - s * ydi2);
            const float yoi2 = 0.5f * (-c * ydi2 + s * ydr2);
            bufA[PHYS(2048 - k)] = make_float2(yer2 - yoi2, yei2 + yor2);
        }
    }
    if (tid == 0) {
        const float2 Y = NB[PHYS(1024)];
        bufA[PHYS(1024)] = make_float2(Y.x, -Y.y);
    }

    float2* w = fft2048<1>(bufA, bufB);    // result in bufA
    const float Dh = Dv[h];
    const float sc = 1.0f / 2048.0f;
    if (fastpath) {
        float2* rowv = (float2*)(ws_rows + (size_t)bh * LSEQ);
        for (int n = tid; n < 1024; n += 256) {
            const float2 wv = w[PHYS(n)];
            const float2 xv = rowv[n];
            rowv[n] = make_float2(wv.x * sc + Dh * xv.x,
                                  wv.y * sc + Dh * xv.y);
        }
    } else {
        const float* ub = u + (size_t)b * LSEQ * HCH + h;
        float* ob = out + (size_t)b * LSEQ * HCH + h;
        for (int n = tid; n < 1024; n += 256) {
            const float2 wv = w[PHYS(n)];
            ob[(size_t)(2 * n) * HCH]     = wv.x * sc + Dh * ub[(size_t)(2 * n) * HCH];
            ob[(size_t)(2 * n + 1) * HCH] = wv.y * sc + Dh * ub[(size_t)(2 * n + 1) * HCH];
        }
    }
}

// ---------------------------------------------------------------------------
// transpose (VERBATIM r2)
// ---------------------------------------------------------------------------
__global__ __launch_bounds__(256)
void transpose_kernel(const float* __restrict__ in, float* __restrict__ out,
                      int rows, int cols)
{
    __shared__ float tile[32][33];
    const int b  = blockIdx.z;
    const int r0 = blockIdx.y << 5;
    const int c0 = blockIdx.x << 5;
    const size_t base = (size_t)b * rows * cols;
    const int tx = threadIdx.x & 31;
    const int ty = threadIdx.x >> 5;
#pragma unroll
    for (int i = 0; i < 32; i += 8)
        tile[ty + i][tx] = in[base + (size_t)(r0 + ty + i) * cols + (c0 + tx)];
    __syncthreads();
#pragma unroll
    for (int i = 0; i < 32; i += 8)
        out[base + (size_t)(c0 + ty + i) * rows + (r0 + tx)] = tile[tx][ty + i];
}

// ---------------------------------------------------------------------------
extern "C" void kernel_launch(void* const* d_in, const int* in_sizes, int n_in,
                              void* d_out, int out_size, void* d_ws, size_t ws_size,
                              hipStream_t stream)
{
    (void)in_sizes; (void)n_in; (void)out_size;
    const float* u  = (const float*)d_in[0];
    const float* Lr = (const float*)d_in[1];
    const float* Li = (const float*)d_in[2];
    const float* Pr = (const float*)d_in[3];
    const float* Pi = (const float*)d_in[4];
    const float* Br = (const float*)d_in[5];
    const float* Bi = (const float*)d_in[6];
    const float* Cr = (const float*)d_in[7];
    const float* Ci = (const float*)d_in[8];
    const float* ld = (const float*)d_in[9];
    const float* Dv = (const float*)d_in[10];
    float* out = (float*)d_out;

    const size_t UT_BYTES = (size_t)NBATCH * HCH * LSEQ * sizeof(float);   // 32 MB
    const size_t KF_BYTES = (size_t)HCH * 2049 * sizeof(float2);           // 8.4 MB
    const int fast = (ws_size >= UT_BYTES + KF_BYTES) ? 1 : 0;             // r2 gate

    float*  ut;
    float2* Kf;
    if (fast) { ut = (float*)d_ws; Kf = (float2*)((char*)d_ws + UT_BYTES); }
    else      { ut = (float*)d_ws; Kf = (float2*)d_ws; }                   // r2 placement

    // THE single new variable vs r2: at staged in d_out[0, 8MB).
    // Dead after s4_kf_kernel; d_out fully rewritten by conv (slow) or L4 (fast).
    float2* at = (float2*)d_out;

    hipLaunchKernelGGL(s4_cauchy_kernel, dim3(HCH * 4), dim3(256), 0, stream,
                       Lr, Li, Pr, Pi, Br, Bi, Cr, Ci, ld, at);
    hipLaunchKernelGGL(s4_kf_kernel, dim3(HCH), dim3(256), 0, stream, at, Kf);
    if (fast) {
        hipLaunchKernelGGL(transpose_kernel, dim3(HCH / 32, LSEQ / 32, NBATCH),
                           dim3(256), 0, stream, u, ut, LSEQ, HCH);
    }
    hipLaunchKernelGGL(s4_conv_kernel, dim3(NBATCH * HCH), dim3(256), 0, stream,
                       u, fast ? ut : nullptr, Kf, Dv, out, fast);
    if (fast) {
        hipLaunchKernelGGL(transpose_kernel, dim3(LSEQ / 32, HCH / 32, NBATCH),
                           dim3(256), 0, stream, ut, out, HCH, LSEQ);
    }
}

// Round 6
// 130.079 us; speedup vs baseline: 1.3491x; 1.0318x over previous
//
#include <hip/hip_runtime.h>
#include <math.h>

#define LSEQ 2048
#define HCH  512
#define NST  64
#define NBATCH 8
#define PIf 3.14159265358979f

// Padded LDS layout: phys(i) = i + i/8 (verified r2)
#define PHYS(i) ((i) + ((i) >> 3))
#define LDSN 2304

__device__ __forceinline__ float2 cmul(float2 a, float2 b) {
    return make_float2(a.x * b.x - a.y * b.y, a.x * b.y + a.y * b.x);
}
__device__ __forceinline__ float2 cadd(float2 a, float2 b) { return make_float2(a.x + b.x, a.y + b.y); }
__device__ __forceinline__ float2 csub(float2 a, float2 b) { return make_float2(a.x - b.x, a.y - b.y); }
__device__ __forceinline__ float2 csq(float2 a) { return make_float2(a.x * a.x - a.y * a.y, 2.f * a.x * a.y); }
template<int INV>
__device__ __forceinline__ float2 rot90(float2 a) {
    return INV ? make_float2(-a.y, a.x) : make_float2(a.y, -a.x);
}

// ---------------------------------------------------------------------------
// Radix-8 Stockham pass, ping-pong (VERBATIM r2 — verified passing).
// ---------------------------------------------------------------------------
template<int INV, int STAGE>
__device__ __forceinline__ void radix8_pass(const float2* __restrict__ src,
                                            float2* __restrict__ dst, int tid)
{
    const int Ns  = 1 << STAGE;
    const int lam = tid & (Ns - 1);
    const int G   = ((tid >> STAGE) << (STAGE + 3)) + lam;

    float2 x0 = src[PHYS(tid)];
    float2 x1 = src[PHYS(tid + 256)];
    float2 x2 = src[PHYS(tid + 512)];
    float2 x3 = src[PHYS(tid + 768)];
    float2 x4 = src[PHYS(tid + 1024)];
    float2 x5 = src[PHYS(tid + 1280)];
    float2 x6 = src[PHYS(tid + 1536)];
    float2 x7 = src[PHYS(tid + 1792)];

    const float SGN = INV ? 1.f : -1.f;
    float sn, cs;
    __sincosf(SGN * (PIf / (float)(4 * Ns)) * (float)lam, &sn, &cs);
    const float2 T3 = make_float2(cs, sn);
    const float2 T2 = csq(T3);
    const float2 T1 = csq(T2);
    const float r2 = 0.70710678118f;
    const float2 U = cmul(T3, make_float2(r2, SGN * r2));

    float2 t;
    t = cmul(T1, x4); float2 a0 = cadd(x0, t), a4 = csub(x0, t);
    t = cmul(T1, x5); float2 a1 = cadd(x1, t), a5 = csub(x1, t);
    t = cmul(T1, x6); float2 a2 = cadd(x2, t), a6 = csub(x2, t);
    t = cmul(T1, x7); float2 a3 = cadd(x3, t), a7 = csub(x3, t);
    t = cmul(T2, a2);             float2 b0 = cadd(a0, t), b2 = csub(a0, t);
    t = cmul(T2, a3);             float2 b1 = cadd(a1, t), b3 = csub(a1, t);
    t = rot90<INV>(cmul(T2, a6)); float2 b4 = cadd(a4, t), b6 = csub(a4, t);
    t = rot90<INV>(cmul(T2, a7)); float2 b5 = cadd(a5, t), b7 = csub(a5, t);
    t = cmul(T3, b1);             dst[PHYS(G)]          = cadd(b0, t); dst[PHYS(G + 4 * Ns)] = csub(b0, t);
    t = rot90<INV>(cmul(T3, b3)); dst[PHYS(G + 2 * Ns)] = cadd(b2, t); dst[PHYS(G + 6 * Ns)] = csub(b2, t);
    t = cmul(U, b5);              dst[PHYS(G + Ns)]     = cadd(b4, t); dst[PHYS(G + 5 * Ns)] = csub(b4, t);
    t = rot90<INV>(cmul(U, b7));  dst[PHYS(G + 3 * Ns)] = cadd(b6, t); dst[PHYS(G + 7 * Ns)] = csub(b6, t);
}

// ---------------------------------------------------------------------------
// 2048-pt FFT, double-buffer ping-pong (VERBATIM r2). Result in bufA.
// ---------------------------------------------------------------------------
template<int INV>
__device__ float2* fft2048(float2* bufA, float2* bufB)
{
    const int tid = threadIdx.x;
    __syncthreads();
    radix8_pass<INV, 0>(bufA, bufB, tid);
    __syncthreads();
    radix8_pass<INV, 3>(bufB, bufA, tid);
    __syncthreads();
    radix8_pass<INV, 6>(bufA, bufB, tid);
    __syncthreads();
    const float SGN = INV ? 1.f : -1.f;
#pragma unroll
    for (int q = 0; q < 2; ++q) {
        const int j = tid + (q << 8);
        float2 A  = bufB[PHYS(j)];
        float2 C  = bufB[PHYS(j + 512)];
        float2 B  = bufB[PHYS(j + 1024)];
        float2 Dd = bufB[PHYS(j + 1536)];
        float sn, cs;
        __sincosf(SGN * (PIf / 1024.f) * (float)j, &sn, &cs);
        const float2 v = make_float2(cs, sn);
        const float2 w = csq(v);
        float2 t = cmul(w, B);  float2 m1 = cadd(A, t), m2 = csub(A, t);
        t = cmul(w, Dd);        float2 m3 = cadd(C, t), m4 = csub(C, t);
        const float2 t3 = cmul(v, m3);
        const float2 t4 = rot90<INV>(cmul(v, m4));
        bufA[PHYS(j)]        = cadd(m1, t3);
        bufA[PHYS(j + 1024)] = csub(m1, t3);
        bufA[PHYS(j + 512)]  = cadd(m2, t4);
        bufA[PHYS(j + 1536)] = csub(m2, t4);
    }
    __syncthreads();
    return bufA;
}

// ---------------------------------------------------------------------------
// Cauchy at_roots — THE single change this round (r3 body, re-verified):
// float4-packed tables, dual l-points per thread in ONE n-loop.
// Block = (h, quarter segment): h = bid>>2, seg = bid&3.
// ---------------------------------------------------------------------------
__global__ __launch_bounds__(256, 4)
void s4_cauchy_kernel(const float* __restrict__ Lr, const float* __restrict__ Li,
                      const float* __restrict__ Pr, const float* __restrict__ Pi,
                      const float* __restrict__ Br, const float* __restrict__ Bi,
                      const float* __restrict__ Cr, const float* __restrict__ Ci,
                      const float* __restrict__ log_dt, float2* __restrict__ at_out)
{
    __shared__ float4 F0[NST];   // (lamRe, lamIm, w00r, w00i)
    __shared__ float4 F1[NST];   // (w01r, w01i, q0r, q0i)
    __shared__ float  q1s[NST];  // |P|^2

    const int h   = blockIdx.x >> 2;
    const int seg = blockIdx.x & 3;
    const int tid = threadIdx.x;

    if (tid < NST) {
        const float pr = Pr[tid], pi = Pi[tid], br = Br[tid], bi = Bi[tid];
        const float cr = Cr[h * NST + tid], ci = Ci[h * NST + tid];
        F0[tid]  = make_float4(Lr[tid], Li[tid], cr * br + ci * bi, cr * bi - ci * br);
        F1[tid]  = make_float4(cr * pr + ci * pi, cr * pi - ci * pr,
                               pr * br + pi * bi, pr * bi - pi * br);
        q1s[tid] = pr * pr + pi * pi;
    }
    __syncthreads();

    const float dt = expf(log_dt[h]);
    const float a  = 2.0f / dt;
    const int l0 = (seg << 9) + tid;
    const int l1 = l0 + 256;
    const float t0 = tanf(PIf * (float)l0 * (1.0f / 2048.0f));
    const float t1 = tanf(PIf * (float)l1 * (1.0f / 2048.0f));
    const float g0 = a * t0, g1 = a * t1;

    float a00r = 0.f, a00i = 0.f, a01r = 0.f, a01i = 0.f;
    float a10r = 0.f, a10i = 0.f, a11r = 0.f, a11i = 0.f;
    float b00r = 0.f, b00i = 0.f, b01r = 0.f, b01i = 0.f;
    float b10r = 0.f, b10i = 0.f, b11r = 0.f, b11i = 0.f;

#pragma unroll 4
    for (int n = 0; n < NST; ++n) {
        const float4 f0 = F0[n];
        const float4 f1 = F1[n];
        const float q1 = q1s[n];
        const float x  = -f0.x;
        const float x2 = x * x;
        {
            const float y = g0 - f0.y;
            const float inv = __builtin_amdgcn_rcpf(x2 + y * y);
            const float rr = x * inv, ri = -y * inv;
            a00r += f0.z * rr - f0.w * ri; a00i += f0.z * ri + f0.w * rr;
            a01r += f1.x * rr - f1.y * ri; a01i += f1.x * ri + f1.y * rr;
            a10r += f1.z * rr - f1.w * ri; a10i += f1.z * ri + f1.w * rr;
            a11r += q1 * rr;               a11i += q1 * ri;
        }
        {
            const float y = g1 - f0.y;
            const float inv = __builtin_amdgcn_rcpf(x2 + y * y);
            const float rr = x * inv, ri = -y * inv;
            b00r += f0.z * rr - f0.w * ri; b00i += f0.z * ri + f0.w * rr;
            b01r += f1.x * rr - f1.y * ri; b01i += f1.x * ri + f1.y * rr;
            b10r += f1.z * rr - f1.w * ri; b10i += f1.z * ri + f1.w * rr;
            b11r += q1 * rr;               b11i += q1 * ri;
        }
    }

    float2* __restrict__ row = at_out + (size_t)h * 2048;
    {
        const float dr = 1.0f + a11r, di = a11i;
        const float dinv = __builtin_amdgcn_rcpf(dr * dr + di * di);
        const float pr_ = a01r * a10r - a01i * a10i;
        const float pi_ = a01r * a10i + a01i * a10r;
        const float qr = (pr_ * dr + pi_ * di) * dinv;
        const float qi = (pi_ * dr - pr_ * di) * dinv;
        const float sr = a00r - qr, si = a00i - qi;
        row[l0] = make_float2(sr - t0 * si, si + t0 * sr);
    }
    {
        const float dr = 1.0f + b11r, di = b11i;
        const float dinv = __builtin_amdgcn_rcpf(dr * dr + di * di);
        const float pr_ = b01r * b10r - b01i * b10i;
        const float pi_ = b01r * b10i + b01i * b10r;
        const float qr = (pr_ * dr + pi_ * di) * dinv;
        const float qi = (pi_ * dr - pr_ * di) * dinv;
        const float sr = b00r - qr, si = b00i - qi;
        row[l1] = make_float2(sr - t1 * si, si + t1 * sr);
    }
}

// ---------------------------------------------------------------------------
// kf kernel (VERBATIM r5).
// ---------------------------------------------------------------------------
__global__ __launch_bounds__(256, 4)
void s4_kf_kernel(const float2* __restrict__ at_in, float2* __restrict__ Kf)
{
    __shared__ float2 bufA[LDSN];
    __shared__ float2 bufB[LDSN];

    const int h   = blockIdx.x;
    const int tid = threadIdx.x;
    const float2* __restrict__ at = at_in + (size_t)h * 2048;

    for (int q = 0; q < 8; ++q) {
        const int l = tid + (q << 8);
        bufA[PHYS(l)] = at[l];
    }

    float2* Kt = fft2048<1>(bufA, bufB);

    const float sc = 1.0f / 2048.0f;
    for (int n = tid; n < 1024; n += 256)
        bufB[PHYS(n)] = make_float2(Kt[PHYS(2 * n)].x * sc, Kt[PHYS(2 * n + 1)].x * sc);
    for (int n = 1024 + tid; n < 2048; n += 256)
        bufB[PHYS(n)] = make_float2(0.f, 0.f);

    float2* Z = fft2048<0>(bufB, bufA);

    float2* __restrict__ out = Kf + (size_t)h * 2049;
    for (int k = tid; k < 1024; k += 256) {
        const float2 Zk = Z[PHYS(k)];
        const float2 Zm = Z[PHYS((2048 - k) & 2047)];
        const float zer = 0.5f * (Zk.x + Zm.x), zei = 0.5f * (Zk.y - Zm.y);
        const float zdr = Zk.x - Zm.x,         zdi = Zk.y + Zm.y;
        const float zor = 0.5f * zdi,          zoi = -0.5f * zdr;
        float s, c;
        __sincosf(-PIf * (float)k * (1.0f / 2048.0f), &s, &c);
        const float txr = c * zor - s * zoi;
        const float txi = c * zoi + s * zor;
        out[k] = make_float2(zer + txr, zei + txi);
        if (k > 0) {
            out[2048 - k] = make_float2(zer - txr, txi - zei);
        } else {
            out[2048] = make_float2(Zk.x - Zk.y, 0.f);
        }
    }
    if (tid == 0) {
        const float2 z = Z[PHYS(1024)];
        out[1024] = make_float2(z.x, -z.y);
    }
}

// ---------------------------------------------------------------------------
// conv kernel (VERBATIM r5).
// ---------------------------------------------------------------------------
__global__ __launch_bounds__(256, 4)
void s4_conv_kernel(const float* __restrict__ u, float* ws_rows,
                    const float2* __restrict__ Kf, const float* __restrict__ Dv,
                    float* __restrict__ out, int fastpath)
{
    __shared__ float2 bufA[LDSN];
    __shared__ float2 bufB[LDSN];
    __shared__ float2 yfN;

    const int bh  = blockIdx.x;
    const int b   = bh >> 9;
    const int h   = bh & 511;
    const int tid = threadIdx.x;

    if (fastpath) {
        const float2* rowv = (const float2*)(ws_rows + (size_t)bh * LSEQ);
        for (int n = tid; n < 1024; n += 256) bufA[PHYS(n)] = rowv[n];
    } else {
        const float* ub = u + (size_t)b * LSEQ * HCH + h;
        for (int n = tid; n < 1024; n += 256)
            bufA[PHYS(n)] = make_float2(ub[(size_t)(2 * n) * HCH],
                                        ub[(size_t)(2 * n + 1) * HCH]);
    }
    for (int n = 1024 + tid; n < 2048; n += 256) bufA[PHYS(n)] = make_float2(0.f, 0.f);

    float2* Z  = fft2048<0>(bufA, bufB);
    float2* NB = bufB;
    const float2* __restrict__ kf = Kf + (size_t)h * 2049;

    for (int k = tid; k < 1024; k += 256) {
        const float2 Zk = Z[PHYS(k)];
        const float2 Zm = Z[PHYS((2048 - k) & 2047)];
        const float zer = 0.5f * (Zk.x + Zm.x), zei = 0.5f * (Zk.y - Zm.y);
        const float zdr = Zk.x - Zm.x,          zdi = Zk.y + Zm.y;
        const float zor = 0.5f * zdi,           zoi = -0.5f * zdr;
        float s, c;
        __sincosf(-PIf * (float)k * (1.0f / 2048.0f), &s, &c);
        const float txr = c * zor - s * zoi;
        const float txi = c * zoi + s * zor;
        const float xr = zer + txr, xi = zei + txi;
        const float2 kk = kf[k];
        NB[PHYS(k)] = make_float2(xr * kk.x - xi * kk.y, xr * kk.y + xi * kk.x);
        if (k > 0) {
            const float mr = zer - txr, mi = txi - zei;
            const float2 km = kf[2048 - k];
            NB[PHYS(2048 - k)] = make_float2(mr * km.x - mi * km.y,
                                             mr * km.y + mi * km.x);
        } else {
            const float x2048 = Zk.x - Zk.y;
            const float2 k2 = kf[2048];
            yfN = make_float2(x2048 * k2.x, x2048 * k2.y);
        }
    }
    if (tid == 0) {
        const float2 z  = Z[PHYS(1024)];
        const float2 kk = kf[1024];
        NB[PHYS(1024)] = make_float2(z.x * kk.x + z.y * kk.y,
                                     z.x * kk.y - z.y * kk.x);
    }
    __syncthreads();

    for (int k = tid; k < 1024; k += 256) {
        const float2 Yk = NB[PHYS(k)];
        const float2 Ym = (k == 0) ? yfN : NB[PHYS(2048 - k)];
        const float yer = 0.5f * (Yk.x + Ym.x), yei = 0.5f * (Yk.y - Ym.y);
        const float ydr = Yk.x - Ym.x,          ydi = Yk.y + Ym.y;
        float s, c;
        __sincosf(PIf * (float)k * (1.0f / 2048.0f), &s, &c);
        const float yor = 0.5f * (c * ydr - s * ydi);
        const float yoi = 0.5f * (c * ydi + s * ydr);
        bufA[PHYS(k)] = make_float2(yer - yoi, yei + yor);
        if (k > 0) {
            const float yer2 = 0.5f * (Ym.x + Yk.x), yei2 = 0.5f * (Ym.y - Yk.y);
            const float ydr2 = Ym.x - Yk.x,          ydi2 = Ym.y + Yk.y;
            const float yor2 = 0.5f * (-c * ydr2 - s * ydi2);
            const float yoi2 = 0.5f * (-c * ydi2 + s * ydr2);
            bufA[PHYS(2048 - k)] = make_float2(yer2 - yoi2, yei2 + yor2);
        }
    }
    if (tid == 0) {
        const float2 Y = NB[PHYS(1024)];
        bufA[PHYS(1024)] = make_float2(Y.x, -Y.y);
    }

    float2* w = fft2048<1>(bufA, bufB);
    const float Dh = Dv[h];
    const float sc = 1.0f / 2048.0f;
    if (fastpath) {
        float2* rowv = (float2*)(ws_rows + (size_t)bh * LSEQ);
        for (int n = tid; n < 1024; n += 256) {
            const float2 wv = w[PHYS(n)];
            const float2 xv = rowv[n];
            rowv[n] = make_float2(wv.x * sc + Dh * xv.x,
                                  wv.y * sc + Dh * xv.y);
        }
    } else {
        const float* ub = u + (size_t)b * LSEQ * HCH + h;
        float* ob = out + (size_t)b * LSEQ * HCH + h;
        for (int n = tid; n < 1024; n += 256) {
            const float2 wv = w[PHYS(n)];
            ob[(size_t)(2 * n) * HCH]     = wv.x * sc + Dh * ub[(size_t)(2 * n) * HCH];
            ob[(size_t)(2 * n + 1) * HCH] = wv.y * sc + Dh * ub[(size_t)(2 * n + 1) * HCH];
        }
    }
}

// ---------------------------------------------------------------------------
// transpose (VERBATIM r5)
// ---------------------------------------------------------------------------
__global__ __launch_bounds__(256)
void transpose_kernel(const float* __restrict__ in, float* __restrict__ out,
                      int rows, int cols)
{
    __shared__ float tile[32][33];
    const int b  = blockIdx.z;
    const int r0 = blockIdx.y << 5;
    const int c0 = blockIdx.x << 5;
    const size_t base = (size_t)b * rows * cols;
    const int tx = threadIdx.x & 31;
    const int ty = threadIdx.x >> 5;
#pragma unroll
    for (int i = 0; i < 32; i += 8)
        tile[ty + i][tx] = in[base + (size_t)(r0 + ty + i) * cols + (c0 + tx)];
    __syncthreads();
#pragma unroll
    for (int i = 0; i < 32; i += 8)
        out[base + (size_t)(c0 + ty + i) * rows + (r0 + tx)] = tile[tx][ty + i];
}

// ---------------------------------------------------------------------------
extern "C" void kernel_launch(void* const* d_in, const int* in_sizes, int n_in,
                              void* d_out, int out_size, void* d_ws, size_t ws_size,
                              hipStream_t stream)
{
    (void)in_sizes; (void)n_in; (void)out_size;
    const float* u  = (const float*)d_in[0];
    const float* Lr = (const float*)d_in[1];
    const float* Li = (const float*)d_in[2];
    const float* Pr = (const float*)d_in[3];
    const float* Pi = (const float*)d_in[4];
    const float* Br = (const float*)d_in[5];
    const float* Bi = (const float*)d_in[6];
    const float* Cr = (const float*)d_in[7];
    const float* Ci = (const float*)d_in[8];
    const float* ld = (const float*)d_in[9];
    const float* Dv = (const float*)d_in[10];
    float* out = (float*)d_out;

    const size_t UT_BYTES = (size_t)NBATCH * HCH * LSEQ * sizeof(float);   // 32 MB
    const size_t KF_BYTES = (size_t)HCH * 2049 * sizeof(float2);           // 8.4 MB
    const int fast = (ws_size >= UT_BYTES + KF_BYTES) ? 1 : 0;             // r2 gate

    float*  ut;
    float2* Kf;
    if (fast) { ut = (float*)d_ws; Kf = (float2*)((char*)d_ws + UT_BYTES); }
    else      { ut = (float*)d_ws; Kf = (float2*)d_ws; }                   // r2 placement

    // at staged in d_out[0, 8MB) — r5-verified placement.
    float2* at = (float2*)d_out;

    hipLaunchKernelGGL(s4_cauchy_kernel, dim3(HCH * 4), dim3(256), 0, stream,
                       Lr, Li, Pr, Pi, Br, Bi, Cr, Ci, ld, at);
    hipLaunchKernelGGL(s4_kf_kernel, dim3(HCH), dim3(256), 0, stream, at, Kf);
    if (fast) {
        hipLaunchKernelGGL(transpose_kernel, dim3(HCH / 32, LSEQ / 32, NBATCH),
                           dim3(256), 0, stream, u, ut, LSEQ, HCH);
    }
    hipLaunchKernelGGL(s4_conv_kernel, dim3(NBATCH * HCH), dim3(256), 0, stream,
                       u, fast ? ut : nullptr, Kf, Dv, out, fast);
    if (fast) {
        hipLaunchKernelGGL(transpose_kernel, dim3(LSEQ / 32, HCH / 32, NBATCH),
                           dim3(256), 0, stream, ut, out, HCH, LSEQ);
    }
}

// Round 7
// 115.876 us; speedup vs baseline: 1.5145x; 1.1226x over previous
//
#include <hip/hip_runtime.h>
#include <math.h>

#define LSEQ 2048
#define HCH  512
#define NST  64
#define NBATCH 8
#define PIf 3.14159265358979f

// Padded LDS layout: phys(i) = i + i/8 (verified r2)
#define PHYS(i) ((i) + ((i) >> 3))
#define LDSN 2304

__device__ __forceinline__ float2 cmul(float2 a, float2 b) {
    return make_float2(a.x * b.x - a.y * b.y, a.x * b.y + a.y * b.x);
}
__device__ __forceinline__ float2 cadd(float2 a, float2 b) { return make_float2(a.x + b.x, a.y + b.y); }
__device__ __forceinline__ float2 csub(float2 a, float2 b) { return make_float2(a.x - b.x, a.y - b.y); }
__device__ __forceinline__ float2 csq(float2 a) { return make_float2(a.x * a.x - a.y * a.y, 2.f * a.x * a.y); }
template<int INV>
__device__ __forceinline__ float2 rot90(float2 a) {
    return INV ? make_float2(-a.y, a.x) : make_float2(a.y, -a.x);
}

// ---------------------------------------------------------------------------
// Radix-8 Stockham pass, ping-pong (VERBATIM r2 — verified passing).
// ---------------------------------------------------------------------------
template<int INV, int STAGE>
__device__ __forceinline__ void radix8_pass(const float2* __restrict__ src,
                                            float2* __restrict__ dst, int tid)
{
    const int Ns  = 1 << STAGE;
    const int lam = tid & (Ns - 1);
    const int G   = ((tid >> STAGE) << (STAGE + 3)) + lam;

    float2 x0 = src[PHYS(tid)];
    float2 x1 = src[PHYS(tid + 256)];
    float2 x2 = src[PHYS(tid + 512)];
    float2 x3 = src[PHYS(tid + 768)];
    float2 x4 = src[PHYS(tid + 1024)];
    float2 x5 = src[PHYS(tid + 1280)];
    float2 x6 = src[PHYS(tid + 1536)];
    float2 x7 = src[PHYS(tid + 1792)];

    const float SGN = INV ? 1.f : -1.f;
    float sn, cs;
    __sincosf(SGN * (PIf / (float)(4 * Ns)) * (float)lam, &sn, &cs);
    const float2 T3 = make_float2(cs, sn);
    const float2 T2 = csq(T3);
    const float2 T1 = csq(T2);
    const float r2 = 0.70710678118f;
    const float2 U = cmul(T3, make_float2(r2, SGN * r2));

    float2 t;
    t = cmul(T1, x4); float2 a0 = cadd(x0, t), a4 = csub(x0, t);
    t = cmul(T1, x5); float2 a1 = cadd(x1, t), a5 = csub(x1, t);
    t = cmul(T1, x6); float2 a2 = cadd(x2, t), a6 = csub(x2, t);
    t = cmul(T1, x7); float2 a3 = cadd(x3, t), a7 = csub(x3, t);
    t = cmul(T2, a2);             float2 b0 = cadd(a0, t), b2 = csub(a0, t);
    t = cmul(T2, a3);             float2 b1 = cadd(a1, t), b3 = csub(a1, t);
    t = rot90<INV>(cmul(T2, a6)); float2 b4 = cadd(a4, t), b6 = csub(a4, t);
    t = rot90<INV>(cmul(T2, a7)); float2 b5 = cadd(a5, t), b7 = csub(a5, t);
    t = cmul(T3, b1);             dst[PHYS(G)]          = cadd(b0, t); dst[PHYS(G + 4 * Ns)] = csub(b0, t);
    t = rot90<INV>(cmul(T3, b3)); dst[PHYS(G + 2 * Ns)] = cadd(b2, t); dst[PHYS(G + 6 * Ns)] = csub(b2, t);
    t = cmul(U, b5);              dst[PHYS(G + Ns)]     = cadd(b4, t); dst[PHYS(G + 5 * Ns)] = csub(b4, t);
    t = rot90<INV>(cmul(U, b7));  dst[PHYS(G + 3 * Ns)] = cadd(b6, t); dst[PHYS(G + 7 * Ns)] = csub(b6, t);
}

// ---------------------------------------------------------------------------
// 2048-pt FFT, double-buffer ping-pong (VERBATIM r2). Result in bufA.
// ---------------------------------------------------------------------------
template<int INV>
__device__ float2* fft2048(float2* bufA, float2* bufB)
{
    const int tid = threadIdx.x;
    __syncthreads();
    radix8_pass<INV, 0>(bufA, bufB, tid);
    __syncthreads();
    radix8_pass<INV, 3>(bufB, bufA, tid);
    __syncthreads();
    radix8_pass<INV, 6>(bufA, bufB, tid);
    __syncthreads();
    const float SGN = INV ? 1.f : -1.f;
#pragma unroll
    for (int q = 0; q < 2; ++q) {
        const int j = tid + (q << 8);
        float2 A  = bufB[PHYS(j)];
        float2 C  = bufB[PHYS(j + 512)];
        float2 B  = bufB[PHYS(j + 1024)];
        float2 Dd = bufB[PHYS(j + 1536)];
        float sn, cs;
        __sincosf(SGN * (PIf / 1024.f) * (float)j, &sn, &cs);
        const float2 v = make_float2(cs, sn);
        const float2 w = csq(v);
        float2 t = cmul(w, B);  float2 m1 = cadd(A, t), m2 = csub(A, t);
        t = cmul(w, Dd);        float2 m3 = cadd(C, t), m4 = csub(C, t);
        const float2 t3 = cmul(v, m3);
        const float2 t4 = rot90<INV>(cmul(v, m4));
        bufA[PHYS(j)]        = cadd(m1, t3);
        bufA[PHYS(j + 1024)] = csub(m1, t3);
        bufA[PHYS(j + 512)]  = cadd(m2, t4);
        bufA[PHYS(j + 1536)] = csub(m2, t4);
    }
    __syncthreads();
    return bufA;
}

// ---------------------------------------------------------------------------
// Cauchy v3 (only change this round): 4 l-points/thread (halves LDS-pipe
// pressure per point), explicit fmaf accumulation (guarantees 2 FMA each).
// Block = (h, half): h = bid>>1, half = bid&1.
// ---------------------------------------------------------------------------
__global__ __launch_bounds__(256, 4)
void s4_cauchy_kernel(const float* __restrict__ Lr, const float* __restrict__ Li,
                      const float* __restrict__ Pr, const float* __restrict__ Pi,
                      const float* __restrict__ Br, const float* __restrict__ Bi,
                      const float* __restrict__ Cr, const float* __restrict__ Ci,
                      const float* __restrict__ log_dt, float2* __restrict__ at_out)
{
    __shared__ float4 F0[NST];   // (lamRe, lamIm, w00r, w00i)
    __shared__ float4 F1[NST];   // (w01r, w01i, q0r, q0i)
    __shared__ float  q1s[NST];  // |P|^2

    const int h    = blockIdx.x >> 1;
    const int half = blockIdx.x & 1;
    const int tid  = threadIdx.x;

    if (tid < NST) {
        const float pr = Pr[tid], pi = Pi[tid], br = Br[tid], bi = Bi[tid];
        const float cr = Cr[h * NST + tid], ci = Ci[h * NST + tid];
        F0[tid]  = make_float4(Lr[tid], Li[tid], cr * br + ci * bi, cr * bi - ci * br);
        F1[tid]  = make_float4(cr * pr + ci * pi, cr * pi - ci * pr,
                               pr * br + pi * bi, pr * bi - pi * br);
        q1s[tid] = pr * pr + pi * pi;
    }
    __syncthreads();

    const float dt = expf(log_dt[h]);
    const float a  = 2.0f / dt;

    float tt[4], g[4];
#pragma unroll
    for (int p = 0; p < 4; ++p) {
        const int l = (half << 10) + (p << 8) + tid;
        tt[p] = tanf(PIf * (float)l * (1.0f / 2048.0f));
        g[p]  = a * tt[p];
    }

    float k00r[4], k00i[4], k01r[4], k01i[4];
    float k10r[4], k10i[4], k11r[4], k11i[4];
#pragma unroll
    for (int p = 0; p < 4; ++p) {
        k00r[p] = 0.f; k00i[p] = 0.f; k01r[p] = 0.f; k01i[p] = 0.f;
        k10r[p] = 0.f; k10i[p] = 0.f; k11r[p] = 0.f; k11i[p] = 0.f;
    }

#pragma unroll 2
    for (int n = 0; n < NST; ++n) {
        const float4 f0 = F0[n];
        const float4 f1 = F1[n];
        const float q1 = q1s[n];
        const float x  = -f0.x;
        const float x2 = x * x;
#pragma unroll
        for (int p = 0; p < 4; ++p) {
            const float y   = g[p] - f0.y;
            const float inv = __builtin_amdgcn_rcpf(fmaf(y, y, x2));
            const float rr  = x * inv;
            const float ri  = -y * inv;
            k00r[p] = fmaf(f0.z, rr, fmaf(-f0.w, ri, k00r[p]));
            k00i[p] = fmaf(f0.z, ri, fmaf( f0.w, rr, k00i[p]));
            k01r[p] = fmaf(f1.x, rr, fmaf(-f1.y, ri, k01r[p]));
            k01i[p] = fmaf(f1.x, ri, fmaf( f1.y, rr, k01i[p]));
            k10r[p] = fmaf(f1.z, rr, fmaf(-f1.w, ri, k10r[p]));
            k10i[p] = fmaf(f1.z, ri, fmaf( f1.w, rr, k10i[p]));
            k11r[p] = fmaf(q1, rr, k11r[p]);
            k11i[p] = fmaf(q1, ri, k11i[p]);
        }
    }

    float2* __restrict__ row = at_out + (size_t)h * 2048;
#pragma unroll
    for (int p = 0; p < 4; ++p) {
        const int l = (half << 10) + (p << 8) + tid;
        const float dr = 1.0f + k11r[p], di = k11i[p];
        const float dinv = __builtin_amdgcn_rcpf(fmaf(dr, dr, di * di));
        const float pr_ = k01r[p] * k10r[p] - k01i[p] * k10i[p];
        const float pi_ = k01r[p] * k10i[p] + k01i[p] * k10r[p];
        const float qr = (pr_ * dr + pi_ * di) * dinv;
        const float qi = (pi_ * dr - pr_ * di) * dinv;
        const float sr = k00r[p] - qr, si = k00i[p] - qi;
        row[l] = make_float2(fmaf(-tt[p], si, sr), fmaf(tt[p], sr, si));
    }
}

// ---------------------------------------------------------------------------
// kf kernel (VERBATIM r5).
// ---------------------------------------------------------------------------
__global__ __launch_bounds__(256, 4)
void s4_kf_kernel(const float2* __restrict__ at_in, float2* __restrict__ Kf)
{
    __shared__ float2 bufA[LDSN];
    __shared__ float2 bufB[LDSN];

    const int h   = blockIdx.x;
    const int tid = threadIdx.x;
    const float2* __restrict__ at = at_in + (size_t)h * 2048;

    for (int q = 0; q < 8; ++q) {
        const int l = tid + (q << 8);
        bufA[PHYS(l)] = at[l];
    }

    float2* Kt = fft2048<1>(bufA, bufB);

    const float sc = 1.0f / 2048.0f;
    for (int n = tid; n < 1024; n += 256)
        bufB[PHYS(n)] = make_float2(Kt[PHYS(2 * n)].x * sc, Kt[PHYS(2 * n + 1)].x * sc);
    for (int n = 1024 + tid; n < 2048; n += 256)
        bufB[PHYS(n)] = make_float2(0.f, 0.f);

    float2* Z = fft2048<0>(bufB, bufA);

    float2* __restrict__ out = Kf + (size_t)h * 2049;
    for (int k = tid; k < 1024; k += 256) {
        const float2 Zk = Z[PHYS(k)];
        const float2 Zm = Z[PHYS((2048 - k) & 2047)];
        const float zer = 0.5f * (Zk.x + Zm.x), zei = 0.5f * (Zk.y - Zm.y);
        const float zdr = Zk.x - Zm.x,         zdi = Zk.y + Zm.y;
        const float zor = 0.5f * zdi,          zoi = -0.5f * zdr;
        float s, c;
        __sincosf(-PIf * (float)k * (1.0f / 2048.0f), &s, &c);
        const float txr = c * zor - s * zoi;
        const float txi = c * zoi + s * zor;
        out[k] = make_float2(zer + txr, zei + txi);
        if (k > 0) {
            out[2048 - k] = make_float2(zer - txr, txi - zei);
        } else {
            out[2048] = make_float2(Zk.x - Zk.y, 0.f);
        }
    }
    if (tid == 0) {
        const float2 z = Z[PHYS(1024)];
        out[1024] = make_float2(z.x, -z.y);
    }
}

// ---------------------------------------------------------------------------
// conv kernel (VERBATIM r5).
// ---------------------------------------------------------------------------
__global__ __launch_bounds__(256, 4)
void s4_conv_kernel(const float* __restrict__ u, float* ws_rows,
                    const float2* __restrict__ Kf, const float* __restrict__ Dv,
                    float* __restrict__ out, int fastpath)
{
    __shared__ float2 bufA[LDSN];
    __shared__ float2 bufB[LDSN];
    __shared__ float2 yfN;

    const int bh  = blockIdx.x;
    const int b   = bh >> 9;
    const int h   = bh & 511;
    const int tid = threadIdx.x;

    if (fastpath) {
        const float2* rowv = (const float2*)(ws_rows + (size_t)bh * LSEQ);
        for (int n = tid; n < 1024; n += 256) bufA[PHYS(n)] = rowv[n];
    } else {
        const float* ub = u + (size_t)b * LSEQ * HCH + h;
        for (int n = tid; n < 1024; n += 256)
            bufA[PHYS(n)] = make_float2(ub[(size_t)(2 * n) * HCH],
                                        ub[(size_t)(2 * n + 1) * HCH]);
    }
    for (int n = 1024 + tid; n < 2048; n += 256) bufA[PHYS(n)] = make_float2(0.f, 0.f);

    float2* Z  = fft2048<0>(bufA, bufB);
    float2* NB = bufB;
    const float2* __restrict__ kf = Kf + (size_t)h * 2049;

    for (int k = tid; k < 1024; k += 256) {
        const float2 Zk = Z[PHYS(k)];
        const float2 Zm = Z[PHYS((2048 - k) & 2047)];
        const float zer = 0.5f * (Zk.x + Zm.x), zei = 0.5f * (Zk.y - Zm.y);
        const float zdr = Zk.x - Zm.x,          zdi = Zk.y + Zm.y;
        const float zor = 0.5f * zdi,           zoi = -0.5f * zdr;
        float s, c;
        __sincosf(-PIf * (float)k * (1.0f / 2048.0f), &s, &c);
        const float txr = c * zor - s * zoi;
        const float txi = c * zoi + s * zor;
        const float xr = zer + txr, xi = zei + txi;
        const float2 kk = kf[k];
        NB[PHYS(k)] = make_float2(xr * kk.x - xi * kk.y, xr * kk.y + xi * kk.x);
        if (k > 0) {
            const float mr = zer - txr, mi = txi - zei;
            const float2 km = kf[2048 - k];
            NB[PHYS(2048 - k)] = make_float2(mr * km.x - mi * km.y,
                                             mr * km.y + mi * km.x);
        } else {
            const float x2048 = Zk.x - Zk.y;
            const float2 k2 = kf[2048];
            yfN = make_float2(x2048 * k2.x, x2048 * k2.y);
        }
    }
    if (tid == 0) {
        const float2 z  = Z[PHYS(1024)];
        const float2 kk = kf[1024];
        NB[PHYS(1024)] = make_float2(z.x * kk.x + z.y * kk.y,
                                     z.x * kk.y - z.y * kk.x);
    }
    __syncthreads();

    for (int k = tid; k < 1024; k += 256) {
        const float2 Yk = NB[PHYS(k)];
        const float2 Ym = (k == 0) ? yfN : NB[PHYS(2048 - k)];
        const float yer = 0.5f * (Yk.x + Ym.x), yei = 0.5f * (Yk.y - Ym.y);
        const float ydr = Yk.x - Ym.x,          ydi = Yk.y + Ym.y;
        float s, c;
        __sincosf(PIf * (float)k * (1.0f / 2048.0f), &s, &c);
        const float yor = 0.5f * (c * ydr - s * ydi);
        const float yoi = 0.5f * (c * ydi + s * ydr);
        bufA[PHYS(k)] = make_float2(yer - yoi, yei + yor);
        if (k > 0) {
            const float yer2 = 0.5f * (Ym.x + Yk.x), yei2 = 0.5f * (Ym.y - Yk.y);
            const float ydr2 = Ym.x - Yk.x,          ydi2 = Ym.y + Yk.y;
            const float yor2 = 0.5f * (-c * ydr2 - s * ydi2);
            const float yoi2 = 0.5f * (-c * ydi2 + s * ydr2);
            bufA[PHYS(2048 - k)] = make_float2(yer2 - yoi2, yei2 + yor2);
        }
    }
    if (tid == 0) {
        const float2 Y = NB[PHYS(1024)];
        bufA[PHYS(1024)] = make_float2(Y.x, -Y.y);
    }

    float2* w = fft2048<1>(bufA, bufB);
    const float Dh = Dv[h];
    const float sc = 1.0f / 2048.0f;
    if (fastpath) {
        float2* rowv = (float2*)(ws_rows + (size_t)bh * LSEQ);
        for (int n = tid; n < 1024; n += 256) {
            const float2 wv = w[PHYS(n)];
            const float2 xv = rowv[n];
            rowv[n] = make_float2(wv.x * sc + Dh * xv.x,
                                  wv.y * sc + Dh * xv.y);
        }
    } else {
        const float* ub = u + (size_t)b * LSEQ * HCH + h;
        float* ob = out + (size_t)b * LSEQ * HCH + h;
        for (int n = tid; n < 1024; n += 256) {
            const float2 wv = w[PHYS(n)];
            ob[(size_t)(2 * n) * HCH]     = wv.x * sc + Dh * ub[(size_t)(2 * n) * HCH];
            ob[(size_t)(2 * n + 1) * HCH] = wv.y * sc + Dh * ub[(size_t)(2 * n + 1) * HCH];
        }
    }
}

// ---------------------------------------------------------------------------
// transpose (VERBATIM r5)
// ---------------------------------------------------------------------------
__global__ __launch_bounds__(256)
void transpose_kernel(const float* __restrict__ in, float* __restrict__ out,
                      int rows, int cols)
{
    __shared__ float tile[32][33];
    const int b  = blockIdx.z;
    const int r0 = blockIdx.y << 5;
    const int c0 = blockIdx.x << 5;
    const size_t base = (size_t)b * rows * cols;
    const int tx = threadIdx.x & 31;
    const int ty = threadIdx.x >> 5;
#pragma unroll
    for (int i = 0; i < 32; i += 8)
        tile[ty + i][tx] = in[base + (size_t)(r0 + ty + i) * cols + (c0 + tx)];
    __syncthreads();
#pragma unroll
    for (int i = 0; i < 32; i += 8)
        out[base + (size_t)(c0 + ty + i) * rows + (r0 + tx)] = tile[tx][ty + i];
}

// ---------------------------------------------------------------------------
extern "C" void kernel_launch(void* const* d_in, const int* in_sizes, int n_in,
                              void* d_out, int out_size, void* d_ws, size_t ws_size,
                              hipStream_t stream)
{
    (void)in_sizes; (void)n_in; (void)out_size;
    const float* u  = (const float*)d_in[0];
    const float* Lr = (const float*)d_in[1];
    const float* Li = (const float*)d_in[2];
    const float* Pr = (const float*)d_in[3];
    const float* Pi = (const float*)d_in[4];
    const float* Br = (const float*)d_in[5];
    const float* Bi = (const float*)d_in[6];
    const float* Cr = (const float*)d_in[7];
    const float* Ci = (const float*)d_in[8];
    const float* ld = (const float*)d_in[9];
    const float* Dv = (const float*)d_in[10];
    float* out = (float*)d_out;

    const size_t UT_BYTES = (size_t)NBATCH * HCH * LSEQ * sizeof(float);   // 32 MB
    const size_t KF_BYTES = (size_t)HCH * 2049 * sizeof(float2);           // 8.4 MB
    const int fast = (ws_size >= UT_BYTES + KF_BYTES) ? 1 : 0;             // r2 gate

    float*  ut;
    float2* Kf;
    if (fast) { ut = (float*)d_ws; Kf = (float2*)((char*)d_ws + UT_BYTES); }
    else      { ut = (float*)d_ws; Kf = (float2*)d_ws; }                   // r2 placement

    // at staged in d_out[0, 8MB) — r5-verified placement.
    float2* at = (float2*)d_out;

    hipLaunchKernelGGL(s4_cauchy_kernel, dim3(HCH * 2), dim3(256), 0, stream,
                       Lr, Li, Pr, Pi, Br, Bi, Cr, Ci, ld, at);
    hipLaunchKernelGGL(s4_kf_kernel, dim3(HCH), dim3(256), 0, stream, at, Kf);
    if (fast) {
        hipLaunchKernelGGL(transpose_kernel, dim3(HCH / 32, LSEQ / 32, NBATCH),
                           dim3(256), 0, stream, u, ut, LSEQ, HCH);
    }
    hipLaunchKernelGGL(s4_conv_kernel, dim3(NBATCH * HCH), dim3(256), 0, stream,
                       u, fast ? ut : nullptr, Kf, Dv, out, fast);
    if (fast) {
        hipLaunchKernelGGL(transpose_kernel, dim3(LSEQ / 32, HCH / 32, NBATCH),
                           dim3(256), 0, stream, ut, out, HCH, LSEQ);
    }
}

// Round 8
// 110.634 us; speedup vs baseline: 1.5862x; 1.0474x over previous
//
#include <hip/hip_runtime.h>
#include <math.h>

#define LSEQ 2048
#define HCH  512
#define NST  64
#define NBATCH 8
#define PIf 3.14159265358979f

// Padded LDS layout: phys(i) = i + i/8 (verified r2)
#define PHYS(i) ((i) + ((i) >> 3))
#define LDSN 2304

__device__ __forceinline__ float2 cmul(float2 a, float2 b) {
    return make_float2(a.x * b.x - a.y * b.y, a.x * b.y + a.y * b.x);
}
__device__ __forceinline__ float2 cadd(float2 a, float2 b) { return make_float2(a.x + b.x, a.y + b.y); }
__device__ __forceinline__ float2 csub(float2 a, float2 b) { return make_float2(a.x - b.x, a.y - b.y); }
__device__ __forceinline__ float2 csq(float2 a) { return make_float2(a.x * a.x - a.y * a.y, 2.f * a.x * a.y); }
template<int INV>
__device__ __forceinline__ float2 rot90(float2 a) {
    return INV ? make_float2(-a.y, a.x) : make_float2(a.y, -a.x);
}

// ---------------------------------------------------------------------------
// Radix-8 Stockham pass, ping-pong (VERBATIM r2 — verified passing).
// ---------------------------------------------------------------------------
template<int INV, int STAGE>
__device__ __forceinline__ void radix8_pass(const float2* __restrict__ src,
                                            float2* __restrict__ dst, int tid)
{
    const int Ns  = 1 << STAGE;
    const int lam = tid & (Ns - 1);
    const int G   = ((tid >> STAGE) << (STAGE + 3)) + lam;

    float2 x0 = src[PHYS(tid)];
    float2 x1 = src[PHYS(tid + 256)];
    float2 x2 = src[PHYS(tid + 512)];
    float2 x3 = src[PHYS(tid + 768)];
    float2 x4 = src[PHYS(tid + 1024)];
    float2 x5 = src[PHYS(tid + 1280)];
    float2 x6 = src[PHYS(tid + 1536)];
    float2 x7 = src[PHYS(tid + 1792)];

    const float SGN = INV ? 1.f : -1.f;
    float sn, cs;
    __sincosf(SGN * (PIf / (float)(4 * Ns)) * (float)lam, &sn, &cs);
    const float2 T3 = make_float2(cs, sn);
    const float2 T2 = csq(T3);
    const float2 T1 = csq(T2);
    const float r2 = 0.70710678118f;
    const float2 U = cmul(T3, make_float2(r2, SGN * r2));

    float2 t;
    t = cmul(T1, x4); float2 a0 = cadd(x0, t), a4 = csub(x0, t);
    t = cmul(T1, x5); float2 a1 = cadd(x1, t), a5 = csub(x1, t);
    t = cmul(T1, x6); float2 a2 = cadd(x2, t), a6 = csub(x2, t);
    t = cmul(T1, x7); float2 a3 = cadd(x3, t), a7 = csub(x3, t);
    t = cmul(T2, a2);             float2 b0 = cadd(a0, t), b2 = csub(a0, t);
    t = cmul(T2, a3);             float2 b1 = cadd(a1, t), b3 = csub(a1, t);
    t = rot90<INV>(cmul(T2, a6)); float2 b4 = cadd(a4, t), b6 = csub(a4, t);
    t = rot90<INV>(cmul(T2, a7)); float2 b5 = cadd(a5, t), b7 = csub(a5, t);
    t = cmul(T3, b1);             dst[PHYS(G)]          = cadd(b0, t); dst[PHYS(G + 4 * Ns)] = csub(b0, t);
    t = rot90<INV>(cmul(T3, b3)); dst[PHYS(G + 2 * Ns)] = cadd(b2, t); dst[PHYS(G + 6 * Ns)] = csub(b2, t);
    t = cmul(U, b5);              dst[PHYS(G + Ns)]     = cadd(b4, t); dst[PHYS(G + 5 * Ns)] = csub(b4, t);
    t = rot90<INV>(cmul(U, b7));  dst[PHYS(G + 3 * Ns)] = cadd(b6, t); dst[PHYS(G + 7 * Ns)] = csub(b6, t);
}

// ---------------------------------------------------------------------------
// 2048-pt FFT, double-buffer ping-pong (VERBATIM r2). Result in bufA.
// Used by kf kernel (unchanged this round).
// ---------------------------------------------------------------------------
template<int INV>
__device__ float2* fft2048(float2* bufA, float2* bufB)
{
    const int tid = threadIdx.x;
    __syncthreads();
    radix8_pass<INV, 0>(bufA, bufB, tid);
    __syncthreads();
    radix8_pass<INV, 3>(bufB, bufA, tid);
    __syncthreads();
    radix8_pass<INV, 6>(bufA, bufB, tid);
    __syncthreads();
    const float SGN = INV ? 1.f : -1.f;
#pragma unroll
    for (int q = 0; q < 2; ++q) {
        const int j = tid + (q << 8);
        float2 A  = bufB[PHYS(j)];
        float2 C  = bufB[PHYS(j + 512)];
        float2 B  = bufB[PHYS(j + 1024)];
        float2 Dd = bufB[PHYS(j + 1536)];
        float sn, cs;
        __sincosf(SGN * (PIf / 1024.f) * (float)j, &sn, &cs);
        const float2 v = make_float2(cs, sn);
        const float2 w = csq(v);
        float2 t = cmul(w, B);  float2 m1 = cadd(A, t), m2 = csub(A, t);
        t = cmul(w, Dd);        float2 m3 = cadd(C, t), m4 = csub(C, t);
        const float2 t3 = cmul(v, m3);
        const float2 t4 = rot90<INV>(cmul(v, m4));
        bufA[PHYS(j)]        = cadd(m1, t3);
        bufA[PHYS(j + 1024)] = csub(m1, t3);
        bufA[PHYS(j + 512)]  = cadd(m2, t4);
        bufA[PHYS(j + 1536)] = csub(m2, t4);
    }
    __syncthreads();
    return bufA;
}

// ---------------------------------------------------------------------------
// In-place FFT machinery (the single new variable this round, conv only):
// radix-8 pass: sync; read 8 strided; sync; scattered write (same indices set).
// ---------------------------------------------------------------------------
template<int INV, int STAGE>
__device__ __forceinline__ void radix8_inplace(float2* __restrict__ buf, int tid)
{
    __syncthreads();
    float2 x0 = buf[PHYS(tid)];
    float2 x1 = buf[PHYS(tid + 256)];
    float2 x2 = buf[PHYS(tid + 512)];
    float2 x3 = buf[PHYS(tid + 768)];
    float2 x4 = buf[PHYS(tid + 1024)];
    float2 x5 = buf[PHYS(tid + 1280)];
    float2 x6 = buf[PHYS(tid + 1536)];
    float2 x7 = buf[PHYS(tid + 1792)];
    __syncthreads();

    const int Ns  = 1 << STAGE;
    const int lam = tid & (Ns - 1);
    const int G   = ((tid >> STAGE) << (STAGE + 3)) + lam;
    const float SGN = INV ? 1.f : -1.f;
    float sn, cs;
    __sincosf(SGN * (PIf / (float)(4 * Ns)) * (float)lam, &sn, &cs);
    const float2 T3 = make_float2(cs, sn);
    const float2 T2 = csq(T3);
    const float2 T1 = csq(T2);
    const float r2 = 0.70710678118f;
    const float2 U = cmul(T3, make_float2(r2, SGN * r2));
    float2 t;
    t = cmul(T1, x4); float2 a0 = cadd(x0, t), a4 = csub(x0, t);
    t = cmul(T1, x5); float2 a1 = cadd(x1, t), a5 = csub(x1, t);
    t = cmul(T1, x6); float2 a2 = cadd(x2, t), a6 = csub(x2, t);
    t = cmul(T1, x7); float2 a3 = cadd(x3, t), a7 = csub(x3, t);
    t = cmul(T2, a2);             float2 b0 = cadd(a0, t), b2 = csub(a0, t);
    t = cmul(T2, a3);             float2 b1 = cadd(a1, t), b3 = csub(a1, t);
    t = rot90<INV>(cmul(T2, a6)); float2 b4 = cadd(a4, t), b6 = csub(a4, t);
    t = rot90<INV>(cmul(T2, a7)); float2 b5 = cadd(a5, t), b7 = csub(a5, t);
    t = cmul(T3, b1);             buf[PHYS(G)]          = cadd(b0, t); buf[PHYS(G + 4 * Ns)] = csub(b0, t);
    t = rot90<INV>(cmul(T3, b3)); buf[PHYS(G + 2 * Ns)] = cadd(b2, t); buf[PHYS(G + 6 * Ns)] = csub(b2, t);
    t = cmul(U, b5);              buf[PHYS(G + Ns)]     = cadd(b4, t); buf[PHYS(G + 5 * Ns)] = csub(b4, t);
    t = rot90<INV>(cmul(U, b7));  buf[PHYS(G + 3 * Ns)] = cadd(b6, t); buf[PHYS(G + 7 * Ns)] = csub(b6, t);
}

// In-place final radix-4 (stages 9,10): butterfly j's read set == write set
// {j, j+512, j+1024, j+1536}; quads are disjoint across j -> entry sync only.
template<int INV>
__device__ __forceinline__ void radix4_inplace(float2* __restrict__ buf, int tid)
{
    __syncthreads();
    const float SGN = INV ? 1.f : -1.f;
#pragma unroll
    for (int q = 0; q < 2; ++q) {
        const int j = tid + (q << 8);
        float2 A  = buf[PHYS(j)];
        float2 C  = buf[PHYS(j + 512)];
        float2 B  = buf[PHYS(j + 1024)];
        float2 Dd = buf[PHYS(j + 1536)];
        float sn, cs;
        __sincosf(SGN * (PIf / 1024.f) * (float)j, &sn, &cs);
        const float2 v = make_float2(cs, sn);
        const float2 w = csq(v);
        float2 t = cmul(w, B);  float2 m1 = cadd(A, t), m2 = csub(A, t);
        t = cmul(w, Dd);        float2 m3 = cadd(C, t), m4 = csub(C, t);
        const float2 t3 = cmul(v, m3);
        const float2 t4 = rot90<INV>(cmul(v, m4));
        buf[PHYS(j)]        = cadd(m1, t3);
        buf[PHYS(j + 1024)] = csub(m1, t3);
        buf[PHYS(j + 512)]  = cadd(m2, t4);
        buf[PHYS(j + 1536)] = csub(m2, t4);
    }
}

template<int INV>
__device__ __forceinline__ void fft2048_ip(float2* buf, int tid)
{
    radix8_inplace<INV, 0>(buf, tid);
    radix8_inplace<INV, 3>(buf, tid);
    radix8_inplace<INV, 6>(buf, tid);
    radix4_inplace<INV>(buf, tid);
}

// ---------------------------------------------------------------------------
// Cauchy (VERBATIM r7 — verified passing).
// ---------------------------------------------------------------------------
__global__ __launch_bounds__(256, 4)
void s4_cauchy_kernel(const float* __restrict__ Lr, const float* __restrict__ Li,
                      const float* __restrict__ Pr, const float* __restrict__ Pi,
                      const float* __restrict__ Br, const float* __restrict__ Bi,
                      const float* __restrict__ Cr, const float* __restrict__ Ci,
                      const float* __restrict__ log_dt, float2* __restrict__ at_out)
{
    __shared__ float4 F0[NST];
    __shared__ float4 F1[NST];
    __shared__ float  q1s[NST];

    const int h    = blockIdx.x >> 1;
    const int half = blockIdx.x & 1;
    const int tid  = threadIdx.x;

    if (tid < NST) {
        const float pr = Pr[tid], pi = Pi[tid], br = Br[tid], bi = Bi[tid];
        const float cr = Cr[h * NST + tid], ci = Ci[h * NST + tid];
        F0[tid]  = make_float4(Lr[tid], Li[tid], cr * br + ci * bi, cr * bi - ci * br);
        F1[tid]  = make_float4(cr * pr + ci * pi, cr * pi - ci * pr,
                               pr * br + pi * bi, pr * bi - pi * br);
        q1s[tid] = pr * pr + pi * pi;
    }
    __syncthreads();

    const float dt = expf(log_dt[h]);
    const float a  = 2.0f / dt;

    float tt[4], g[4];
#pragma unroll
    for (int p = 0; p < 4; ++p) {
        const int l = (half << 10) + (p << 8) + tid;
        tt[p] = tanf(PIf * (float)l * (1.0f / 2048.0f));
        g[p]  = a * tt[p];
    }

    float k00r[4], k00i[4], k01r[4], k01i[4];
    float k10r[4], k10i[4], k11r[4], k11i[4];
#pragma unroll
    for (int p = 0; p < 4; ++p) {
        k00r[p] = 0.f; k00i[p] = 0.f; k01r[p] = 0.f; k01i[p] = 0.f;
        k10r[p] = 0.f; k10i[p] = 0.f; k11r[p] = 0.f; k11i[p] = 0.f;
    }

#pragma unroll 2
    for (int n = 0; n < NST; ++n) {
        const float4 f0 = F0[n];
        const float4 f1 = F1[n];
        const float q1 = q1s[n];
        const float x  = -f0.x;
        const float x2 = x * x;
#pragma unroll
        for (int p = 0; p < 4; ++p) {
            const float y   = g[p] - f0.y;
            const float inv = __builtin_amdgcn_rcpf(fmaf(y, y, x2));
            const float rr  = x * inv;
            const float ri  = -y * inv;
            k00r[p] = fmaf(f0.z, rr, fmaf(-f0.w, ri, k00r[p]));
            k00i[p] = fmaf(f0.z, ri, fmaf( f0.w, rr, k00i[p]));
            k01r[p] = fmaf(f1.x, rr, fmaf(-f1.y, ri, k01r[p]));
            k01i[p] = fmaf(f1.x, ri, fmaf( f1.y, rr, k01i[p]));
            k10r[p] = fmaf(f1.z, rr, fmaf(-f1.w, ri, k10r[p]));
            k10i[p] = fmaf(f1.z, ri, fmaf( f1.w, rr, k10i[p]));
            k11r[p] = fmaf(q1, rr, k11r[p]);
            k11i[p] = fmaf(q1, ri, k11i[p]);
        }
    }

    float2* __restrict__ row = at_out + (size_t)h * 2048;
#pragma unroll
    for (int p = 0; p < 4; ++p) {
        const int l = (half << 10) + (p << 8) + tid;
        const float dr = 1.0f + k11r[p], di = k11i[p];
        const float dinv = __builtin_amdgcn_rcpf(fmaf(dr, dr, di * di));
        const float pr_ = k01r[p] * k10r[p] - k01i[p] * k10i[p];
        const float pi_ = k01r[p] * k10i[p] + k01i[p] * k10r[p];
        const float qr = (pr_ * dr + pi_ * di) * dinv;
        const float qi = (pi_ * dr - pr_ * di) * dinv;
        const float sr = k00r[p] - qr, si = k00i[p] - qi;
        row[l] = make_float2(fmaf(-tt[p], si, sr), fmaf(tt[p], sr, si));
    }
}

// ---------------------------------------------------------------------------
// kf kernel (VERBATIM r7).
// ---------------------------------------------------------------------------
__global__ __launch_bounds__(256, 4)
void s4_kf_kernel(const float2* __restrict__ at_in, float2* __restrict__ Kf)
{
    __shared__ float2 bufA[LDSN];
    __shared__ float2 bufB[LDSN];

    const int h   = blockIdx.x;
    const int tid = threadIdx.x;
    const float2* __restrict__ at = at_in + (size_t)h * 2048;

    for (int q = 0; q < 8; ++q) {
        const int l = tid + (q << 8);
        bufA[PHYS(l)] = at[l];
    }

    float2* Kt = fft2048<1>(bufA, bufB);

    const float sc = 1.0f / 2048.0f;
    for (int n = tid; n < 1024; n += 256)
        bufB[PHYS(n)] = make_float2(Kt[PHYS(2 * n)].x * sc, Kt[PHYS(2 * n + 1)].x * sc);
    for (int n = 1024 + tid; n < 2048; n += 256)
        bufB[PHYS(n)] = make_float2(0.f, 0.f);

    float2* Z = fft2048<0>(bufB, bufA);

    float2* __restrict__ out = Kf + (size_t)h * 2049;
    for (int k = tid; k < 1024; k += 256) {
        const float2 Zk = Z[PHYS(k)];
        const float2 Zm = Z[PHYS((2048 - k) & 2047)];
        const float zer = 0.5f * (Zk.x + Zm.x), zei = 0.5f * (Zk.y - Zm.y);
        const float zdr = Zk.x - Zm.x,         zdi = Zk.y + Zm.y;
        const float zor = 0.5f * zdi,          zoi = -0.5f * zdr;
        float s, c;
        __sincosf(-PIf * (float)k * (1.0f / 2048.0f), &s, &c);
        const float txr = c * zor - s * zoi;
        const float txi = c * zoi + s * zor;
        out[k] = make_float2(zer + txr, zei + txi);
        if (k > 0) {
            out[2048 - k] = make_float2(zer - txr, txi - zei);
        } else {
            out[2048] = make_float2(Zk.x - Zk.y, 0.f);
        }
    }
    if (tid == 0) {
        const float2 z = Z[PHYS(1024)];
        out[1024] = make_float2(z.x, -z.y);
    }
}

// ---------------------------------------------------------------------------
// conv kernel — in-place single-buffer version. Phase math VERBATIM r2/r7;
// each phase converted to read-regs -> sync -> write-in-place.
// ---------------------------------------------------------------------------
__global__ __launch_bounds__(256, 6)
void s4_conv_kernel(const float* __restrict__ u, float* ws_rows,
                    const float2* __restrict__ Kf, const float* __restrict__ Dv,
                    float* __restrict__ out, int fastpath)
{
    __shared__ float2 buf[LDSN];
    __shared__ float2 yfN;   // Yf[2048]

    const int bh  = blockIdx.x;
    const int b   = bh >> 9;
    const int h   = bh & 511;
    const int tid = threadIdx.x;

    // pack x: z[n] = x[2n] + i x[2n+1], zero tail
    if (fastpath) {
        const float2* rowv = (const float2*)(ws_rows + (size_t)bh * LSEQ);
        for (int n = tid; n < 1024; n += 256) buf[PHYS(n)] = rowv[n];
    } else {
        const float* ub = u + (size_t)b * LSEQ * HCH + h;
        for (int n = tid; n < 1024; n += 256)
            buf[PHYS(n)] = make_float2(ub[(size_t)(2 * n) * HCH],
                                       ub[(size_t)(2 * n + 1) * HCH]);
    }
    for (int n = 1024 + tid; n < 2048; n += 256) buf[PHYS(n)] = make_float2(0.f, 0.f);

    fft2048_ip<0>(buf, tid);   // entry sync covers pack writes; Z in buf

    const float2* __restrict__ kf = Kf + (size_t)h * 2049;

    // Phase M: Yf[k] = Xf[k]*Kf[k]   (read Z -> regs; sync; write Yf in place)
    __syncthreads();
    float2 Zk[4], Zm[4], Z1024v;
#pragma unroll
    for (int q = 0; q < 4; ++q) {
        const int k = tid + (q << 8);
        Zk[q] = buf[PHYS(k)];
        Zm[q] = buf[PHYS((2048 - k) & 2047)];
    }
    if (tid == 0) Z1024v = buf[PHYS(1024)];
    __syncthreads();
#pragma unroll
    for (int q = 0; q < 4; ++q) {
        const int k = tid + (q << 8);
        const float2 zk = Zk[q], zm = Zm[q];
        const float zer = 0.5f * (zk.x + zm.x), zei = 0.5f * (zk.y - zm.y);
        const float zdr = zk.x - zm.x,          zdi = zk.y + zm.y;
        const float zor = 0.5f * zdi,           zoi = -0.5f * zdr;
        float s, c;
        __sincosf(-PIf * (float)k * (1.0f / 2048.0f), &s, &c);
        const float txr = c * zor - s * zoi;
        const float txi = c * zoi + s * zor;
        const float xr = zer + txr, xi = zei + txi;        // Xf[k]
        const float2 kk = kf[k];
        buf[PHYS(k)] = make_float2(xr * kk.x - xi * kk.y, xr * kk.y + xi * kk.x);
        if (k > 0) {
            const float mr = zer - txr, mi = txi - zei;    // Xf[2048-k]
            const float2 km = kf[2048 - k];
            buf[PHYS(2048 - k)] = make_float2(mr * km.x - mi * km.y,
                                              mr * km.y + mi * km.x);
        } else {
            const float x2048 = zk.x - zk.y;               // Xf[2048] (real)
            const float2 k2 = kf[2048];
            yfN = make_float2(x2048 * k2.x, x2048 * k2.y);
        }
    }
    if (tid == 0) {
        const float2 kk = kf[1024];
        buf[PHYS(1024)] = make_float2(Z1024v.x * kk.x + Z1024v.y * kk.y,
                                      Z1024v.x * kk.y - Z1024v.y * kk.x);
    }

    // Phase R: W[k] = Ye[k] + i*Yo[k]   (read Yf -> regs; sync; write W in place)
    __syncthreads();
    float2 Yk[4], Ym[4], Y1024v;
#pragma unroll
    for (int q = 0; q < 4; ++q) {
        const int k = tid + (q << 8);
        Yk[q] = buf[PHYS(k)];
        Ym[q] = (k == 0) ? yfN : buf[PHYS(2048 - k)];
    }
    if (tid == 0) Y1024v = buf[PHYS(1024)];
    __syncthreads();
#pragma unroll
    for (int q = 0; q < 4; ++q) {
        const int k = tid + (q << 8);
        const float2 yk = Yk[q], ym = Ym[q];
        const float yer = 0.5f * (yk.x + ym.x), yei = 0.5f * (yk.y - ym.y);
        const float ydr = yk.x - ym.x,          ydi = yk.y + ym.y;
        float s, c;
        __sincosf(PIf * (float)k * (1.0f / 2048.0f), &s, &c);
        const float yor = 0.5f * (c * ydr - s * ydi);
        const float yoi = 0.5f * (c * ydi + s * ydr);
        buf[PHYS(k)] = make_float2(yer - yoi, yei + yor);
        if (k > 0) {
            const float yer2 = 0.5f * (ym.x + yk.x), yei2 = 0.5f * (ym.y - yk.y);
            const float ydr2 = ym.x - yk.x,          ydi2 = ym.y + yk.y;
            const float yor2 = 0.5f * (-c * ydr2 - s * ydi2);
            const float yoi2 = 0.5f * (-c * ydi2 + s * ydr2);
            buf[PHYS(2048 - k)] = make_float2(yer2 - yoi2, yei2 + yor2);
        }
    }
    if (tid == 0) {
        buf[PHYS(1024)] = make_float2(Y1024v.x, -Y1024v.y);
    }

    fft2048_ip<1>(buf, tid);   // entry sync covers Phase R writes; w in buf

    __syncthreads();
    const float Dh = Dv[h];
    const float sc = 1.0f / 2048.0f;
    if (fastpath) {
        float2* rowv = (float2*)(ws_rows + (size_t)bh * LSEQ);
        for (int n = tid; n < 1024; n += 256) {
            const float2 wv = buf[PHYS(n)];
            const float2 xv = rowv[n];
            rowv[n] = make_float2(wv.x * sc + Dh * xv.x,
                                  wv.y * sc + Dh * xv.y);
        }
    } else {
        const float* ub = u + (size_t)b * LSEQ * HCH + h;
        float* ob = out + (size_t)b * LSEQ * HCH + h;
        for (int n = tid; n < 1024; n += 256) {
            const float2 wv = buf[PHYS(n)];
            ob[(size_t)(2 * n) * HCH]     = wv.x * sc + Dh * ub[(size_t)(2 * n) * HCH];
            ob[(size_t)(2 * n + 1) * HCH] = wv.y * sc + Dh * ub[(size_t)(2 * n + 1) * HCH];
        }
    }
}

// ---------------------------------------------------------------------------
// transpose (VERBATIM r7)
// ---------------------------------------------------------------------------
__global__ __launch_bounds__(256)
void transpose_kernel(const float* __restrict__ in, float* __restrict__ out,
                      int rows, int cols)
{
    __shared__ float tile[32][33];
    const int b  = blockIdx.z;
    const int r0 = blockIdx.y << 5;
    const int c0 = blockIdx.x << 5;
    const size_t base = (size_t)b * rows * cols;
    const int tx = threadIdx.x & 31;
    const int ty = threadIdx.x >> 5;
#pragma unroll
    for (int i = 0; i < 32; i += 8)
        tile[ty + i][tx] = in[base + (size_t)(r0 + ty + i) * cols + (c0 + tx)];
    __syncthreads();
#pragma unroll
    for (int i = 0; i < 32; i += 8)
        out[base + (size_t)(c0 + ty + i) * rows + (r0 + tx)] = tile[tx][ty + i];
}

// ---------------------------------------------------------------------------
extern "C" void kernel_launch(void* const* d_in, const int* in_sizes, int n_in,
                              void* d_out, int out_size, void* d_ws, size_t ws_size,
                              hipStream_t stream)
{
    (void)in_sizes; (void)n_in; (void)out_size;
    const float* u  = (const float*)d_in[0];
    const float* Lr = (const float*)d_in[1];
    const float* Li = (const float*)d_in[2];
    const float* Pr = (const float*)d_in[3];
    const float* Pi = (const float*)d_in[4];
    const float* Br = (const float*)d_in[5];
    const float* Bi = (const float*)d_in[6];
    const float* Cr = (const float*)d_in[7];
    const float* Ci = (const float*)d_in[8];
    const float* ld = (const float*)d_in[9];
    const float* Dv = (const float*)d_in[10];
    float* out = (float*)d_out;

    const size_t UT_BYTES = (size_t)NBATCH * HCH * LSEQ * sizeof(float);   // 32 MB
    const size_t KF_BYTES = (size_t)HCH * 2049 * sizeof(float2);           // 8.4 MB
    const int fast = (ws_size >= UT_BYTES + KF_BYTES) ? 1 : 0;             // r2 gate

    float*  ut;
    float2* Kf;
    if (fast) { ut = (float*)d_ws; Kf = (float2*)((char*)d_ws + UT_BYTES); }
    else      { ut = (float*)d_ws; Kf = (float2*)d_ws; }                   // r2 placement

    // at staged in d_out[0, 8MB) — r5-verified placement.
    float2* at = (float2*)d_out;

    hipLaunchKernelGGL(s4_cauchy_kernel, dim3(HCH * 2), dim3(256), 0, stream,
                       Lr, Li, Pr, Pi, Br, Bi, Cr, Ci, ld, at);
    hipLaunchKernelGGL(s4_kf_kernel, dim3(HCH), dim3(256), 0, stream, at, Kf);
    if (fast) {
        hipLaunchKernelGGL(transpose_kernel, dim3(HCH / 32, LSEQ / 32, NBATCH),
                           dim3(256), 0, stream, u, ut, LSEQ, HCH);
    }
    hipLaunchKernelGGL(s4_conv_kernel, dim3(NBATCH * HCH), dim3(256), 0, stream,
                       u, fast ? ut : nullptr, Kf, Dv, out, fast);
    if (fast) {
        hipLaunchKernelGGL(transpose_kernel, dim3(LSEQ / 32, HCH / 32, NBATCH),
                           dim3(256), 0, stream, ut, out, HCH, LSEQ);
    }
}

// Round 9
// 109.305 us; speedup vs baseline: 1.6055x; 1.0122x over previous
//
#include <hip/hip_runtime.h>
#include <math.h>

#define LSEQ 2048
#define HCH  512
#define NST  64
#define NBATCH 8
#define PIf 3.14159265358979f

// Padded LDS layout: phys(i) = i + i/8 (verified r2)
#define PHYS(i) ((i) + ((i) >> 3))
#define LDSN 2304

__device__ __forceinline__ float2 cmul(float2 a, float2 b) {
    return make_float2(a.x * b.x - a.y * b.y, a.x * b.y + a.y * b.x);
}
__device__ __forceinline__ float2 cadd(float2 a, float2 b) { return make_float2(a.x + b.x, a.y + b.y); }
__device__ __forceinline__ float2 csub(float2 a, float2 b) { return make_float2(a.x - b.x, a.y - b.y); }
__device__ __forceinline__ float2 csq(float2 a) { return make_float2(a.x * a.x - a.y * a.y, 2.f * a.x * a.y); }
template<int INV>
__device__ __forceinline__ float2 rot90(float2 a) {
    return INV ? make_float2(-a.y, a.x) : make_float2(a.y, -a.x);
}

// ---------------------------------------------------------------------------
// Radix-8 Stockham pass, ping-pong (VERBATIM r2). Used by kf kernel.
// ---------------------------------------------------------------------------
template<int INV, int STAGE>
__device__ __forceinline__ void radix8_pass(const float2* __restrict__ src,
                                            float2* __restrict__ dst, int tid)
{
    const int Ns  = 1 << STAGE;
    const int lam = tid & (Ns - 1);
    const int G   = ((tid >> STAGE) << (STAGE + 3)) + lam;

    float2 x0 = src[PHYS(tid)];
    float2 x1 = src[PHYS(tid + 256)];
    float2 x2 = src[PHYS(tid + 512)];
    float2 x3 = src[PHYS(tid + 768)];
    float2 x4 = src[PHYS(tid + 1024)];
    float2 x5 = src[PHYS(tid + 1280)];
    float2 x6 = src[PHYS(tid + 1536)];
    float2 x7 = src[PHYS(tid + 1792)];

    const float SGN = INV ? 1.f : -1.f;
    float sn, cs;
    __sincosf(SGN * (PIf / (float)(4 * Ns)) * (float)lam, &sn, &cs);
    const float2 T3 = make_float2(cs, sn);
    const float2 T2 = csq(T3);
    const float2 T1 = csq(T2);
    const float r2 = 0.70710678118f;
    const float2 U = cmul(T3, make_float2(r2, SGN * r2));

    float2 t;
    t = cmul(T1, x4); float2 a0 = cadd(x0, t), a4 = csub(x0, t);
    t = cmul(T1, x5); float2 a1 = cadd(x1, t), a5 = csub(x1, t);
    t = cmul(T1, x6); float2 a2 = cadd(x2, t), a6 = csub(x2, t);
    t = cmul(T1, x7); float2 a3 = cadd(x3, t), a7 = csub(x3, t);
    t = cmul(T2, a2);             float2 b0 = cadd(a0, t), b2 = csub(a0, t);
    t = cmul(T2, a3);             float2 b1 = cadd(a1, t), b3 = csub(a1, t);
    t = rot90<INV>(cmul(T2, a6)); float2 b4 = cadd(a4, t), b6 = csub(a4, t);
    t = rot90<INV>(cmul(T2, a7)); float2 b5 = cadd(a5, t), b7 = csub(a5, t);
    t = cmul(T3, b1);             dst[PHYS(G)]          = cadd(b0, t); dst[PHYS(G + 4 * Ns)] = csub(b0, t);
    t = rot90<INV>(cmul(T3, b3)); dst[PHYS(G + 2 * Ns)] = cadd(b2, t); dst[PHYS(G + 6 * Ns)] = csub(b2, t);
    t = cmul(U, b5);              dst[PHYS(G + Ns)]     = cadd(b4, t); dst[PHYS(G + 5 * Ns)] = csub(b4, t);
    t = rot90<INV>(cmul(U, b7));  dst[PHYS(G + 3 * Ns)] = cadd(b6, t); dst[PHYS(G + 7 * Ns)] = csub(b6, t);
}

template<int INV>
__device__ float2* fft2048(float2* bufA, float2* bufB)
{
    const int tid = threadIdx.x;
    __syncthreads();
    radix8_pass<INV, 0>(bufA, bufB, tid);
    __syncthreads();
    radix8_pass<INV, 3>(bufB, bufA, tid);
    __syncthreads();
    radix8_pass<INV, 6>(bufA, bufB, tid);
    __syncthreads();
    const float SGN = INV ? 1.f : -1.f;
#pragma unroll
    for (int q = 0; q < 2; ++q) {
        const int j = tid + (q << 8);
        float2 A  = bufB[PHYS(j)];
        float2 C  = bufB[PHYS(j + 512)];
        float2 B  = bufB[PHYS(j + 1024)];
        float2 Dd = bufB[PHYS(j + 1536)];
        float sn, cs;
        __sincosf(SGN * (PIf / 1024.f) * (float)j, &sn, &cs);
        const float2 v = make_float2(cs, sn);
        const float2 w = csq(v);
        float2 t = cmul(w, B);  float2 m1 = cadd(A, t), m2 = csub(A, t);
        t = cmul(w, Dd);        float2 m3 = cadd(C, t), m4 = csub(C, t);
        const float2 t3 = cmul(v, m3);
        const float2 t4 = rot90<INV>(cmul(v, m4));
        bufA[PHYS(j)]        = cadd(m1, t3);
        bufA[PHYS(j + 1024)] = csub(m1, t3);
        bufA[PHYS(j + 512)]  = cadd(m2, t4);
        bufA[PHYS(j + 1536)] = csub(m2, t4);
    }
    __syncthreads();
    return bufA;
}

// ---------------------------------------------------------------------------
// In-place FFT machinery (verified r8).
// ---------------------------------------------------------------------------
template<int INV, int STAGE>
__device__ __forceinline__ void radix8_inplace(float2* __restrict__ buf, int tid)
{
    __syncthreads();
    float2 x0 = buf[PHYS(tid)];
    float2 x1 = buf[PHYS(tid + 256)];
    float2 x2 = buf[PHYS(tid + 512)];
    float2 x3 = buf[PHYS(tid + 768)];
    float2 x4 = buf[PHYS(tid + 1024)];
    float2 x5 = buf[PHYS(tid + 1280)];
    float2 x6 = buf[PHYS(tid + 1536)];
    float2 x7 = buf[PHYS(tid + 1792)];
    __syncthreads();

    const int Ns  = 1 << STAGE;
    const int lam = tid & (Ns - 1);
    const int G   = ((tid >> STAGE) << (STAGE + 3)) + lam;
    const float SGN = INV ? 1.f : -1.f;
    float sn, cs;
    __sincosf(SGN * (PIf / (float)(4 * Ns)) * (float)lam, &sn, &cs);
    const float2 T3 = make_float2(cs, sn);
    const float2 T2 = csq(T3);
    const float2 T1 = csq(T2);
    const float r2 = 0.70710678118f;
    const float2 U = cmul(T3, make_float2(r2, SGN * r2));
    float2 t;
    t = cmul(T1, x4); float2 a0 = cadd(x0, t), a4 = csub(x0, t);
    t = cmul(T1, x5); float2 a1 = cadd(x1, t), a5 = csub(x1, t);
    t = cmul(T1, x6); float2 a2 = cadd(x2, t), a6 = csub(x2, t);
    t = cmul(T1, x7); float2 a3 = cadd(x3, t), a7 = csub(x3, t);
    t = cmul(T2, a2);             float2 b0 = cadd(a0, t), b2 = csub(a0, t);
    t = cmul(T2, a3);             float2 b1 = cadd(a1, t), b3 = csub(a1, t);
    t = rot90<INV>(cmul(T2, a6)); float2 b4 = cadd(a4, t), b6 = csub(a4, t);
    t = rot90<INV>(cmul(T2, a7)); float2 b5 = cadd(a5, t), b7 = csub(a5, t);
    t = cmul(T3, b1);             buf[PHYS(G)]          = cadd(b0, t); buf[PHYS(G + 4 * Ns)] = csub(b0, t);
    t = rot90<INV>(cmul(T3, b3)); buf[PHYS(G + 2 * Ns)] = cadd(b2, t); buf[PHYS(G + 6 * Ns)] = csub(b2, t);
    t = cmul(U, b5);              buf[PHYS(G + Ns)]     = cadd(b4, t); buf[PHYS(G + 5 * Ns)] = csub(b4, t);
    t = rot90<INV>(cmul(U, b7));  buf[PHYS(G + 3 * Ns)] = cadd(b6, t); buf[PHYS(G + 7 * Ns)] = csub(b6, t);
}

template<int INV>
__device__ __forceinline__ void radix4_inplace(float2* __restrict__ buf, int tid)
{
    __syncthreads();
    const float SGN = INV ? 1.f : -1.f;
#pragma unroll
    for (int q = 0; q < 2; ++q) {
        const int j = tid + (q << 8);
        float2 A  = buf[PHYS(j)];
        float2 C  = buf[PHYS(j + 512)];
        float2 B  = buf[PHYS(j + 1024)];
        float2 Dd = buf[PHYS(j + 1536)];
        float sn, cs;
        __sincosf(SGN * (PIf / 1024.f) * (float)j, &sn, &cs);
        const float2 v = make_float2(cs, sn);
        const float2 w = csq(v);
        float2 t = cmul(w, B);  float2 m1 = cadd(A, t), m2 = csub(A, t);
        t = cmul(w, Dd);        float2 m3 = cadd(C, t), m4 = csub(C, t);
        const float2 t3 = cmul(v, m3);
        const float2 t4 = rot90<INV>(cmul(v, m4));
        buf[PHYS(j)]        = cadd(m1, t3);
        buf[PHYS(j + 1024)] = csub(m1, t3);
        buf[PHYS(j + 512)]  = cadd(m2, t4);
        buf[PHYS(j + 1536)] = csub(m2, t4);
    }
}

template<int INV>
__device__ __forceinline__ void fft2048_ip(float2* buf, int tid)
{
    radix8_inplace<INV, 0>(buf, tid);
    radix8_inplace<INV, 3>(buf, tid);
    radix8_inplace<INV, 6>(buf, tid);
    radix4_inplace<INV>(buf, tid);
}

// ---------------------------------------------------------------------------
// Cauchy (VERBATIM r7).
// ---------------------------------------------------------------------------
__global__ __launch_bounds__(256, 4)
void s4_cauchy_kernel(const float* __restrict__ Lr, const float* __restrict__ Li,
                      const float* __restrict__ Pr, const float* __restrict__ Pi,
                      const float* __restrict__ Br, const float* __restrict__ Bi,
                      const float* __restrict__ Cr, const float* __restrict__ Ci,
                      const float* __restrict__ log_dt, float2* __restrict__ at_out)
{
    __shared__ float4 F0[NST];
    __shared__ float4 F1[NST];
    __shared__ float  q1s[NST];

    const int h    = blockIdx.x >> 1;
    const int half = blockIdx.x & 1;
    const int tid  = threadIdx.x;

    if (tid < NST) {
        const float pr = Pr[tid], pi = Pi[tid], br = Br[tid], bi = Bi[tid];
        const float cr = Cr[h * NST + tid], ci = Ci[h * NST + tid];
        F0[tid]  = make_float4(Lr[tid], Li[tid], cr * br + ci * bi, cr * bi - ci * br);
        F1[tid]  = make_float4(cr * pr + ci * pi, cr * pi - ci * pr,
                               pr * br + pi * bi, pr * bi - pi * br);
        q1s[tid] = pr * pr + pi * pi;
    }
    __syncthreads();

    const float dt = expf(log_dt[h]);
    const float a  = 2.0f / dt;

    float tt[4], g[4];
#pragma unroll
    for (int p = 0; p < 4; ++p) {
        const int l = (half << 10) + (p << 8) + tid;
        tt[p] = tanf(PIf * (float)l * (1.0f / 2048.0f));
        g[p]  = a * tt[p];
    }

    float k00r[4], k00i[4], k01r[4], k01i[4];
    float k10r[4], k10i[4], k11r[4], k11i[4];
#pragma unroll
    for (int p = 0; p < 4; ++p) {
        k00r[p] = 0.f; k00i[p] = 0.f; k01r[p] = 0.f; k01i[p] = 0.f;
        k10r[p] = 0.f; k10i[p] = 0.f; k11r[p] = 0.f; k11i[p] = 0.f;
    }

#pragma unroll 2
    for (int n = 0; n < NST; ++n) {
        const float4 f0 = F0[n];
        const float4 f1 = F1[n];
        const float q1 = q1s[n];
        const float x  = -f0.x;
        const float x2 = x * x;
#pragma unroll
        for (int p = 0; p < 4; ++p) {
            const float y   = g[p] - f0.y;
            const float inv = __builtin_amdgcn_rcpf(fmaf(y, y, x2));
            const float rr  = x * inv;
            const float ri  = -y * inv;
            k00r[p] = fmaf(f0.z, rr, fmaf(-f0.w, ri, k00r[p]));
            k00i[p] = fmaf(f0.z, ri, fmaf( f0.w, rr, k00i[p]));
            k01r[p] = fmaf(f1.x, rr, fmaf(-f1.y, ri, k01r[p]));
            k01i[p] = fmaf(f1.x, ri, fmaf( f1.y, rr, k01i[p]));
            k10r[p] = fmaf(f1.z, rr, fmaf(-f1.w, ri, k10r[p]));
            k10i[p] = fmaf(f1.z, ri, fmaf( f1.w, rr, k10i[p]));
            k11r[p] = fmaf(q1, rr, k11r[p]);
            k11i[p] = fmaf(q1, ri, k11i[p]);
        }
    }

    float2* __restrict__ row = at_out + (size_t)h * 2048;
#pragma unroll
    for (int p = 0; p < 4; ++p) {
        const int l = (half << 10) + (p << 8) + tid;
        const float dr = 1.0f + k11r[p], di = k11i[p];
        const float dinv = __builtin_amdgcn_rcpf(fmaf(dr, dr, di * di));
        const float pr_ = k01r[p] * k10r[p] - k01i[p] * k10i[p];
        const float pi_ = k01r[p] * k10i[p] + k01i[p] * k10r[p];
        const float qr = (pr_ * dr + pi_ * di) * dinv;
        const float qi = (pi_ * dr - pr_ * di) * dinv;
        const float sr = k00r[p] - qr, si = k00i[p] - qi;
        row[l] = make_float2(fmaf(-tt[p], si, sr), fmaf(tt[p], sr, si));
    }
}

// ---------------------------------------------------------------------------
// kf kernel (VERBATIM r7).
// ---------------------------------------------------------------------------
__global__ __launch_bounds__(256, 4)
void s4_kf_kernel(const float2* __restrict__ at_in, float2* __restrict__ Kf)
{
    __shared__ float2 bufA[LDSN];
    __shared__ float2 bufB[LDSN];

    const int h   = blockIdx.x;
    const int tid = threadIdx.x;
    const float2* __restrict__ at = at_in + (size_t)h * 2048;

    for (int q = 0; q < 8; ++q) {
        const int l = tid + (q << 8);
        bufA[PHYS(l)] = at[l];
    }

    float2* Kt = fft2048<1>(bufA, bufB);

    const float sc = 1.0f / 2048.0f;
    for (int n = tid; n < 1024; n += 256)
        bufB[PHYS(n)] = make_float2(Kt[PHYS(2 * n)].x * sc, Kt[PHYS(2 * n + 1)].x * sc);
    for (int n = 1024 + tid; n < 2048; n += 256)
        bufB[PHYS(n)] = make_float2(0.f, 0.f);

    float2* Z = fft2048<0>(bufB, bufA);

    float2* __restrict__ out = Kf + (size_t)h * 2049;
    for (int k = tid; k < 1024; k += 256) {
        const float2 Zk = Z[PHYS(k)];
        const float2 Zm = Z[PHYS((2048 - k) & 2047)];
        const float zer = 0.5f * (Zk.x + Zm.x), zei = 0.5f * (Zk.y - Zm.y);
        const float zdr = Zk.x - Zm.x,         zdi = Zk.y + Zm.y;
        const float zor = 0.5f * zdi,          zoi = -0.5f * zdr;
        float s, c;
        __sincosf(-PIf * (float)k * (1.0f / 2048.0f), &s, &c);
        const float txr = c * zor - s * zoi;
        const float txi = c * zoi + s * zor;
        out[k] = make_float2(zer + txr, zei + txi);
        if (k > 0) {
            out[2048 - k] = make_float2(zer - txr, txi - zei);
        } else {
            out[2048] = make_float2(Zk.x - Zk.y, 0.f);
        }
    }
    if (tid == 0) {
        const float2 z = Z[PHYS(1024)];
        out[1024] = make_float2(z.x, -z.y);
    }
}

// ---------------------------------------------------------------------------
// conv kernel — r8 in-place structure + FUSED multiply+repack (the single
// new variable this round; algebra re-verified against the passing r8 split).
// ---------------------------------------------------------------------------
__global__ __launch_bounds__(256, 6)
void s4_conv_kernel(const float* __restrict__ u, float* ws_rows,
                    const float2* __restrict__ Kf, const float* __restrict__ Dv,
                    float* __restrict__ out, int fastpath)
{
    __shared__ float2 buf[LDSN];

    const int bh  = blockIdx.x;
    const int b   = bh >> 9;
    const int h   = bh & 511;
    const int tid = threadIdx.x;

    // pack x: z[n] = x[2n] + i x[2n+1], zero tail
    if (fastpath) {
        const float2* rowv = (const float2*)(ws_rows + (size_t)bh * LSEQ);
        for (int n = tid; n < 1024; n += 256) buf[PHYS(n)] = rowv[n];
    } else {
        const float* ub = u + (size_t)b * LSEQ * HCH + h;
        for (int n = tid; n < 1024; n += 256)
            buf[PHYS(n)] = make_float2(ub[(size_t)(2 * n) * HCH],
                                       ub[(size_t)(2 * n + 1) * HCH]);
    }
    for (int n = 1024 + tid; n < 2048; n += 256) buf[PHYS(n)] = make_float2(0.f, 0.f);

    fft2048_ip<0>(buf, tid);   // Z in buf

    const float2* __restrict__ kf = Kf + (size_t)h * 2049;

    // FUSED phase: read Z -> regs; sync; compute Yf=Xf*Kf and write W in place.
    __syncthreads();
    float2 Zk[4], Zm[4], Z1024v;
#pragma unroll
    for (int q = 0; q < 4; ++q) {
        const int k = tid + (q << 8);
        Zk[q] = buf[PHYS(k)];
        Zm[q] = buf[PHYS((2048 - k) & 2047)];
    }
    if (tid == 0) Z1024v = buf[PHYS(1024)];
    __syncthreads();

#pragma unroll
    for (int q = 0; q < 4; ++q) {
        const int k = tid + (q << 8);
        const float2 zk = Zk[q], zm = Zm[q];
        const float zer = 0.5f * (zk.x + zm.x), zei = 0.5f * (zk.y - zm.y);
        const float zdr = zk.x - zm.x,          zdi = zk.y + zm.y;
        const float zor = 0.5f * zdi,           zoi = -0.5f * zdr;
        float s, c;
        __sincosf(-PIf * (float)k * (1.0f / 2048.0f), &s, &c);   // s = -sin(pi k/2048)
        const float txr = c * zor - s * zoi;
        const float txi = c * zoi + s * zor;
        const float2 Xk = make_float2(zer + txr, zei + txi);     // Xf[k]
        float2 Yk = cmul(Xk, kf[k]);
        float2 Ym;
        if (k > 0) {
            const float2 Xm = make_float2(zer - txr, txi - zei); // Xf[2048-k]
            Ym = cmul(Xm, kf[2048 - k]);
        } else {
            const float x2048 = zk.x - zk.y;                     // Xf[2048] (real)
            const float2 k2 = kf[2048];
            Ym = make_float2(x2048 * k2.x, x2048 * k2.y);        // Y[2048]
        }
        // Repack: W[k] = E[k] + i O[k], with Y[k+2048] = conj(Y[2048-k]).
        const float yer = 0.5f * (Yk.x + Ym.x), yei = 0.5f * (Yk.y - Ym.y);
        const float ydr = Yk.x - Ym.x,          ydi = Yk.y + Ym.y;
        // need (c, sin(+pi k/2048)) = (c, -s): yor = (c*ydr + s*ydi)/2, etc.
        const float yor = 0.5f * (c * ydr + s * ydi);
        const float yoi = 0.5f * (c * ydi - s * ydr);
        buf[PHYS(k)] = make_float2(yer - yoi, yei + yor);
        if (k > 0)
            buf[PHYS(2048 - k)] = make_float2(yer + yoi, yor - yei);
    }
    if (tid == 0) {
        const float2 kk = kf[1024];
        // Y[1024] = conj(Z[1024]) * kf[1024]; W[1024] = conj(Y[1024])
        const float2 y = make_float2(Z1024v.x * kk.x + Z1024v.y * kk.y,
                                     Z1024v.x * kk.y - Z1024v.y * kk.x);
        buf[PHYS(1024)] = make_float2(y.x, -y.y);
    }

    fft2048_ip<1>(buf, tid);   // entry sync covers fused-phase writes; w in buf

    __syncthreads();
    const float Dh = Dv[h];
    const float sc = 1.0f / 2048.0f;
    if (fastpath) {
        float2* rowv = (float2*)(ws_rows + (size_t)bh * LSEQ);
        for (int n = tid; n < 1024; n += 256) {
            const float2 wv = buf[PHYS(n)];
            const float2 xv = rowv[n];
            rowv[n] = make_float2(wv.x * sc + Dh * xv.x,
                                  wv.y * sc + Dh * xv.y);
        }
    } else {
        const float* ub = u + (size_t)b * LSEQ * HCH + h;
        float* ob = out + (size_t)b * LSEQ * HCH + h;
        for (int n = tid; n < 1024; n += 256) {
            const float2 wv = buf[PHYS(n)];
            ob[(size_t)(2 * n) * HCH]     = wv.x * sc + Dh * ub[(size_t)(2 * n) * HCH];
            ob[(size_t)(2 * n + 1) * HCH] = wv.y * sc + Dh * ub[(size_t)(2 * n + 1) * HCH];
        }
    }
}

// ---------------------------------------------------------------------------
// transpose (VERBATIM r7)
// ---------------------------------------------------------------------------
__global__ __launch_bounds__(256)
void transpose_kernel(const float* __restrict__ in, float* __restrict__ out,
                      int rows, int cols)
{
    __shared__ float tile[32][33];
    const int b  = blockIdx.z;
    const int r0 = blockIdx.y << 5;
    const int c0 = blockIdx.x << 5;
    const size_t base = (size_t)b * rows * cols;
    const int tx = threadIdx.x & 31;
    const int ty = threadIdx.x >> 5;
#pragma unroll
    for (int i = 0; i < 32; i += 8)
        tile[ty + i][tx] = in[base + (size_t)(r0 + ty + i) * cols + (c0 + tx)];
    __syncthreads();
#pragma unroll
    for (int i = 0; i < 32; i += 8)
        out[base + (size_t)(c0 + ty + i) * rows + (r0 + tx)] = tile[tx][ty + i];
}

// ---------------------------------------------------------------------------
extern "C" void kernel_launch(void* const* d_in, const int* in_sizes, int n_in,
                              void* d_out, int out_size, void* d_ws, size_t ws_size,
                              hipStream_t stream)
{
    (void)in_sizes; (void)n_in; (void)out_size;
    const float* u  = (const float*)d_in[0];
    const float* Lr = (const float*)d_in[1];
    const float* Li = (const float*)d_in[2];
    const float* Pr = (const float*)d_in[3];
    const float* Pi = (const float*)d_in[4];
    const float* Br = (const float*)d_in[5];
    const float* Bi = (const float*)d_in[6];
    const float* Cr = (const float*)d_in[7];
    const float* Ci = (const float*)d_in[8];
    const float* ld = (const float*)d_in[9];
    const float* Dv = (const float*)d_in[10];
    float* out = (float*)d_out;

    const size_t UT_BYTES = (size_t)NBATCH * HCH * LSEQ * sizeof(float);   // 32 MB
    const size_t KF_BYTES = (size_t)HCH * 2049 * sizeof(float2);           // 8.4 MB
    const int fast = (ws_size >= UT_BYTES + KF_BYTES) ? 1 : 0;

    float*  ut;
    float2* Kf;
    if (fast) { ut = (float*)d_ws; Kf = (float2*)((char*)d_ws + UT_BYTES); }
    else      { ut = (float*)d_ws; Kf = (float2*)d_ws; }

    // at staged in d_out[0, 8MB) — r5-verified placement.
    float2* at = (float2*)d_out;

    hipLaunchKernelGGL(s4_cauchy_kernel, dim3(HCH * 2), dim3(256), 0, stream,
                       Lr, Li, Pr, Pi, Br, Bi, Cr, Ci, ld, at);
    hipLaunchKernelGGL(s4_kf_kernel, dim3(HCH), dim3(256), 0, stream, at, Kf);
    if (fast) {
        hipLaunchKernelGGL(transpose_kernel, dim3(HCH / 32, LSEQ / 32, NBATCH),
                           dim3(256), 0, stream, u, ut, LSEQ, HCH);
    }
    hipLaunchKernelGGL(s4_conv_kernel, dim3(NBATCH * HCH), dim3(256), 0, stream,
                       u, fast ? ut : nullptr, Kf, Dv, out, fast);
    if (fast) {
        hipLaunchKernelGGL(transpose_kernel, dim3(LSEQ / 32, HCH / 32, NBATCH),
                           dim3(256), 0, stream, ut, out, HCH, LSEQ);
    }
}